// Round 2
// baseline (777.393 us; speedup 1.0000x reference)
//
#include <hip/hip_runtime.h>
#include <hip/hip_bf16.h>

#define NN   100000
#define EE   1250000
#define DIN  128
#define HID  64
#define DOUT 40

__global__ __launch_bounds__(256) void k_deg_init(float* __restrict__ deg) {
    int i = blockIdx.x * 256 + threadIdx.x;
    if (i < NN) deg[i] = 1.0f;   // self-loop
}

__global__ __launch_bounds__(256) void k_deg_accum(const int* __restrict__ dst,
                                                   float* __restrict__ deg) {
    int e = blockIdx.x * 256 + threadIdx.x;
    if (e < EE) atomicAdd(&deg[dst[e]], 1.0f);
}

__global__ __launch_bounds__(256) void k_dinv(float* __restrict__ deg) {
    int i = blockIdx.x * 256 + threadIdx.x;
    if (i < NN) deg[i] = rsqrtf(deg[i]);   // deg >= 1
}

// XW1 = x @ W1 ; agg1 = XW1 * dinv^2 (self-loop term). 4 rows per 256-thread block.
__global__ __launch_bounds__(256) void k_gemm1(const float* __restrict__ x,
                                               const float* __restrict__ W1,
                                               const float* __restrict__ dinv,
                                               float* __restrict__ xw1,
                                               float* __restrict__ agg1) {
    __shared__ float sw[DIN][HID];   // 32 KB
    __shared__ float sx[4][DIN];     // 2 KB
    int t = threadIdx.x;
    // W1 is 8192 floats: 32 float4s per lane-group; stage vectorized
    const float4* w4 = (const float4*)W1;
    float4* sw4 = (float4*)sw;
    for (int i = t; i < DIN * HID / 4; i += 256) sw4[i] = w4[i];
    int row0 = blockIdx.x * 4;
    // 4 rows x 128 = 512 floats = 128 float4s
    for (int i = t; i < 4 * DIN / 4; i += 256) {
        int r = i >> 5;            // 32 float4 per row
        int k4 = i & 31;
        int row = row0 + r;
        float4 v = (row < NN) ? ((const float4*)(x + row * DIN))[k4]
                              : make_float4(0.f, 0.f, 0.f, 0.f);
        ((float4*)sx[r])[k4] = v;
    }
    __syncthreads();
    int r = t >> 6;        // 0..3
    int c = t & 63;        // channel
    int row = row0 + r;
    if (row >= NN) return;
    float acc = 0.0f;
    #pragma unroll
    for (int k = 0; k < DIN; ++k) acc += sx[r][k] * sw[k][c];
    xw1[row * HID + c] = acc;
    float di = dinv[row];
    agg1[row * HID + c] = acc * di * di;
}

// one wave per edge, lane = channel (64 channels)
__global__ __launch_bounds__(256) void k_scatter1(const int* __restrict__ src,
                                                  const int* __restrict__ dst,
                                                  const float* __restrict__ dinv,
                                                  const float* __restrict__ xw1,
                                                  float* __restrict__ agg1) {
    int e = blockIdx.x * 4 + (threadIdx.x >> 6);
    if (e >= EE) return;
    int lane = threadIdx.x & 63;
    int s = src[e], d = dst[e];
    float nrm = dinv[s] * dinv[d];
    atomicAdd(&agg1[d * HID + lane], xw1[s * HID + lane] * nrm);
}

// HW2 = relu(agg1 + b1) @ W2 ; out = HW2 * dinv^2 + b2 (self-loop + bias).
// 32 rows per 256-thread block.
__global__ __launch_bounds__(256) void k_gemm2(const float* __restrict__ agg1,
                                               const float* __restrict__ b1,
                                               const float* __restrict__ W2,
                                               const float* __restrict__ dinv,
                                               const float* __restrict__ b2,
                                               float* __restrict__ hw2,
                                               float* __restrict__ out) {
    __shared__ float sh[32][HID + 1];   // +1 pad: avoid stride-64 bank conflicts
    __shared__ float sw[HID][DOUT];
    __shared__ float sb1[HID];
    __shared__ float sb2[DOUT];
    int t = threadIdx.x;
    if (t < HID) sb1[t] = b1[t];
    if (t >= HID && t < HID + DOUT) sb2[t - HID] = b2[t - HID];
    for (int i = t; i < HID * DOUT; i += 256)
        sw[i / DOUT][i % DOUT] = W2[i];
    __syncthreads();   // sb1 ready before sh fill
    int row0 = blockIdx.x * 32;
    for (int i = t; i < 32 * HID; i += 256) {
        int r = i >> 6, c = i & 63;
        int row = row0 + r;
        float v = (row < NN) ? agg1[row * HID + c] + sb1[c] : 0.0f;
        sh[r][c] = fmaxf(v, 0.0f);
    }
    __syncthreads();
    int r  = t >> 3;    // 0..31
    int jg = t & 7;     // 8 groups x 5 cols
    int row = row0 + r;
    if (row >= NN) return;
    float di = dinv[row], di2 = di * di;
    #pragma unroll
    for (int j0 = 0; j0 < 5; ++j0) {
        int j = jg * 5 + j0;
        float acc = 0.0f;
        #pragma unroll
        for (int c = 0; c < HID; ++c) acc += sh[r][c] * sw[c][j];
        hw2[row * DOUT + j] = acc;
        out[row * DOUT + j] = acc * di2 + sb2[j];
    }
}

// one wave per edge, lanes 0..39 active; accumulates directly into d_out
__global__ __launch_bounds__(256) void k_scatter2(const int* __restrict__ src,
                                                  const int* __restrict__ dst,
                                                  const float* __restrict__ dinv,
                                                  const float* __restrict__ hw2,
                                                  float* __restrict__ out) {
    int e = blockIdx.x * 4 + (threadIdx.x >> 6);
    int lane = threadIdx.x & 63;
    if (e >= EE || lane >= DOUT) return;
    int s = src[e], d = dst[e];
    float nrm = dinv[s] * dinv[d];
    atomicAdd(&out[d * DOUT + lane], hw2[s * DOUT + lane] * nrm);
}

extern "C" void kernel_launch(void* const* d_in, const int* in_sizes, int n_in,
                              void* d_out, int out_size, void* d_ws, size_t ws_size,
                              hipStream_t stream) {
    const float* x  = (const float*)d_in[0];
    const float* W1 = (const float*)d_in[1];
    const float* b1 = (const float*)d_in[2];
    const float* W2 = (const float*)d_in[3];
    const float* b2 = (const float*)d_in[4];
    const int*   ei = (const int*)d_in[5];
    const int* src = ei;        // edge_index[0]
    const int* dst = ei + EE;   // edge_index[1]
    float* out = (float*)d_out;

    float* ws   = (float*)d_ws;
    float* deg  = ws;                  // NN floats (becomes dinv in place)
    float* xw1  = deg  + NN;           // NN*64
    float* agg1 = xw1  + NN * HID;     // NN*64
    float* hw2  = agg1 + NN * HID;     // NN*40
    // total ws use: NN*(1+64+64+40)*4 B = 67.6 MB

    k_deg_init <<<(NN + 255) / 256, 256, 0, stream>>>(deg);
    k_deg_accum<<<(EE + 255) / 256, 256, 0, stream>>>(dst, deg);
    k_dinv     <<<(NN + 255) / 256, 256, 0, stream>>>(deg);
    k_gemm1    <<<(NN + 3) / 4,     256, 0, stream>>>(x, W1, deg, xw1, agg1);
    k_scatter1 <<<(EE + 3) / 4,     256, 0, stream>>>(src, dst, deg, xw1, agg1);
    k_gemm2    <<<(NN + 31) / 32,   256, 0, stream>>>(agg1, b1, W2, deg, b2, hw2, out);
    k_scatter2 <<<(EE + 3) / 4,     256, 0, stream>>>(src, dst, deg, hw2, out);
}

// Round 3
// 486.939 us; speedup vs baseline: 1.5965x; 1.5965x over previous
//
#include <hip/hip_runtime.h>

#define NN   100000
#define EE   1250000
#define DIN  128
#define HID  64
#define DOUT 40

// ---------------- degree / CSR construction ----------------

__global__ __launch_bounds__(256) void k_zero(int* __restrict__ cnt) {
    int i = blockIdx.x * 256 + threadIdx.x;
    if (i < NN) cnt[i] = 0;
}

__global__ __launch_bounds__(256) void k_count(const int* __restrict__ dst,
                                               int* __restrict__ cnt) {
    int e = blockIdx.x * 256 + threadIdx.x;
    if (e < EE) atomicAdd(&cnt[dst[e]], 1);
}

__global__ __launch_bounds__(256) void k_dinv(const int* __restrict__ cnt,
                                              float* __restrict__ dinv) {
    int i = blockIdx.x * 256 + threadIdx.x;
    if (i < NN) dinv[i] = rsqrtf((float)cnt[i] + 1.0f);  // +1 self-loop
}

// exclusive scan of cnt[NN] -> offs, 512 elems/block
__global__ __launch_bounds__(512) void k_scan1(const int* __restrict__ cnt,
                                               int* __restrict__ offs,
                                               int* __restrict__ bsum) {
    __shared__ int a[512], b[512];
    int t = threadIdx.x;
    int g = blockIdx.x * 512 + t;
    int v = (g < NN) ? cnt[g] : 0;
    a[t] = v;
    int* s = a; int* d = b;
    for (int off = 1; off < 512; off <<= 1) {
        __syncthreads();
        d[t] = s[t] + ((t >= off) ? s[t - off] : 0);
        int* tmp = s; s = d; d = tmp;
    }
    // each thread reads its own element: no extra sync needed
    int incl = s[t];
    if (g < NN) offs[g] = incl - v;            // block-local exclusive
    if (t == 511) bsum[blockIdx.x] = incl;     // block total
}

__global__ __launch_bounds__(256) void k_scan2(const int* __restrict__ bsum,
                                               int* __restrict__ bsum_s, int nblk) {
    __shared__ int a[256], b[256];
    int t = threadIdx.x;
    int v = (t < nblk) ? bsum[t] : 0;
    a[t] = v;
    int* s = a; int* d = b;
    for (int off = 1; off < 256; off <<= 1) {
        __syncthreads();
        d[t] = s[t] + ((t >= off) ? s[t - off] : 0);
        int* tmp = s; s = d; d = tmp;
    }
    if (t < nblk) bsum_s[t] = s[t] - v;        // exclusive
}

__global__ __launch_bounds__(256) void k_scan3(int* __restrict__ offs,
                                               int* __restrict__ cursor,
                                               const int* __restrict__ bsum_s) {
    int i = blockIdx.x * 256 + threadIdx.x;
    if (i < NN) {
        int v = offs[i] + bsum_s[i >> 9];
        offs[i] = v;
        cursor[i] = v;
    } else if (i == NN) {
        offs[NN] = EE;
    }
}

__global__ __launch_bounds__(256) void k_bin(const int* __restrict__ src,
                                             const int* __restrict__ dst,
                                             int* __restrict__ cursor,
                                             int* __restrict__ esrc) {
    int e = blockIdx.x * 256 + threadIdx.x;
    if (e < EE) {
        int d = dst[e];
        int p = atomicAdd(&cursor[d], 1);
        esrc[p] = src[e];
    }
}

// ---------------- layer 1 GEMM: xw1 = x @ W1 ----------------
// block 256 = 4 waves, 64 rows/block; thread = 4 rows x 4 channels, all b128 LDS.
__global__ __launch_bounds__(256) void k_gemm1(const float* __restrict__ x,
                                               const float* __restrict__ W1,
                                               float* __restrict__ xw1) {
    __shared__ float sw[DIN * HID];     // [k][c], 32 KB
    __shared__ float sx[64 * 132];      // rows padded to 132 floats (33 float4)
    int t = threadIdx.x;
    const float4* w4g = (const float4*)W1;
    float4* sw4 = (float4*)sw;
    #pragma unroll
    for (int j = 0; j < 8; ++j) sw4[t + j * 256] = w4g[t + j * 256];
    int row0 = blockIdx.x * 64;
    float4* sx4 = (float4*)sx;
    #pragma unroll
    for (int j = 0; j < 8; ++j) {
        int idx = t + j * 256;          // 2048 float4 = 64 rows x 32
        int r = idx >> 5, k4 = idx & 31;
        int row = row0 + r;
        float4 v = (row < NN) ? ((const float4*)(x + (size_t)row * DIN))[k4]
                              : make_float4(0.f, 0.f, 0.f, 0.f);
        sx4[r * 33 + k4] = v;
    }
    __syncthreads();
    int tx = t & 15;        // channel group: c = tx*4 .. +3
    int rg = t >> 4;        // row group: rows rg*4 .. +3
    float4 acc[4];
    #pragma unroll
    for (int r4 = 0; r4 < 4; ++r4) acc[r4] = make_float4(0.f, 0.f, 0.f, 0.f);
    for (int k0 = 0; k0 < DIN; k0 += 4) {
        float4 w0 = sw4[(k0 + 0) * 16 + tx];
        float4 w1 = sw4[(k0 + 1) * 16 + tx];
        float4 w2 = sw4[(k0 + 2) * 16 + tx];
        float4 w3 = sw4[(k0 + 3) * 16 + tx];
        #pragma unroll
        for (int r4 = 0; r4 < 4; ++r4) {
            float4 xv = sx4[(rg * 4 + r4) * 33 + (k0 >> 2)];
            acc[r4].x += xv.x * w0.x + xv.y * w1.x + xv.z * w2.x + xv.w * w3.x;
            acc[r4].y += xv.x * w0.y + xv.y * w1.y + xv.z * w2.y + xv.w * w3.y;
            acc[r4].z += xv.x * w0.z + xv.y * w1.z + xv.z * w2.z + xv.w * w3.z;
            acc[r4].w += xv.x * w0.w + xv.y * w1.w + xv.z * w2.w + xv.w * w3.w;
        }
    }
    #pragma unroll
    for (int r4 = 0; r4 < 4; ++r4) {
        int row = row0 + rg * 4 + r4;
        if (row < NN) ((float4*)(xw1 + (size_t)row * HID))[tx] = acc[r4];
    }
}

// ---------------- layer 1 aggregation (gather) ----------------
// wave per dst node, lane = channel. agg1 = dd*(dd*xw1[d] + sum dinv[s]*xw1[s])
__global__ __launch_bounds__(256) void k_agg1(const float* __restrict__ xw1,
                                              const float* __restrict__ dinv,
                                              const int* __restrict__ offs,
                                              const int* __restrict__ esrc,
                                              float* __restrict__ agg1) {
    int d = blockIdx.x * 4 + (threadIdx.x >> 6);
    if (d >= NN) return;
    int c = threadIdx.x & 63;
    float dd = dinv[d];
    float acc = dd * xw1[(size_t)d * HID + c];
    int base = offs[d], end = offs[d + 1];
    int j = base;
    for (; j + 1 < end; j += 2) {
        int s0 = esrc[j], s1 = esrc[j + 1];
        float w0 = dinv[s0], w1 = dinv[s1];
        float v0 = xw1[(size_t)s0 * HID + c];
        float v1 = xw1[(size_t)s1 * HID + c];
        acc += w0 * v0;
        acc += w1 * v1;
    }
    if (j < end) {
        int s = esrc[j];
        acc += dinv[s] * xw1[(size_t)s * HID + c];
    }
    agg1[(size_t)d * HID + c] = dd * acc;
}

// ---------------- layer 2 GEMM: hw2 = relu(agg1+b1) @ W2 ----------------
__global__ __launch_bounds__(256) void k_gemm2(const float* __restrict__ agg1,
                                               const float* __restrict__ b1,
                                               const float* __restrict__ W2,
                                               float* __restrict__ hw2) {
    __shared__ float sh[64 * 68];        // rows padded to 68 floats (17 float4)
    __shared__ float sw2l[HID * DOUT];   // [k][j], 10 KB
    int t = threadIdx.x;
    const float4* w4g = (const float4*)W2;
    float4* sw4 = (float4*)sw2l;
    for (int i = t; i < HID * DOUT / 4; i += 256) sw4[i] = w4g[i];
    int row0 = blockIdx.x * 64;
    float4* sh4 = (float4*)sh;
    const float4* b14 = (const float4*)b1;
    #pragma unroll
    for (int j = 0; j < 4; ++j) {
        int idx = t + j * 256;           // 1024 float4 = 64 rows x 16
        int r = idx >> 4, c4 = idx & 15;
        int row = row0 + r;
        float4 v = (row < NN) ? ((const float4*)(agg1 + (size_t)row * HID))[c4]
                              : make_float4(0.f, 0.f, 0.f, 0.f);
        float4 bb = b14[c4];
        v.x = fmaxf(v.x + bb.x, 0.f);
        v.y = fmaxf(v.y + bb.y, 0.f);
        v.z = fmaxf(v.z + bb.z, 0.f);
        v.w = fmaxf(v.w + bb.w, 0.f);
        sh4[r * 17 + c4] = v;
    }
    __syncthreads();
    int tx = t & 15;        // 10 active channel groups
    int rg = t >> 4;
    if (tx < 10) {
        float4 acc[4];
        #pragma unroll
        for (int r4 = 0; r4 < 4; ++r4) acc[r4] = make_float4(0.f, 0.f, 0.f, 0.f);
        for (int k0 = 0; k0 < HID; k0 += 4) {
            float4 w0 = sw4[(k0 + 0) * 10 + tx];
            float4 w1 = sw4[(k0 + 1) * 10 + tx];
            float4 w2 = sw4[(k0 + 2) * 10 + tx];
            float4 w3 = sw4[(k0 + 3) * 10 + tx];
            #pragma unroll
            for (int r4 = 0; r4 < 4; ++r4) {
                float4 xv = sh4[(rg * 4 + r4) * 17 + (k0 >> 2)];
                acc[r4].x += xv.x * w0.x + xv.y * w1.x + xv.z * w2.x + xv.w * w3.x;
                acc[r4].y += xv.x * w0.y + xv.y * w1.y + xv.z * w2.y + xv.w * w3.y;
                acc[r4].z += xv.x * w0.z + xv.y * w1.z + xv.z * w2.z + xv.w * w3.z;
                acc[r4].w += xv.x * w0.w + xv.y * w1.w + xv.z * w2.w + xv.w * w3.w;
            }
        }
        #pragma unroll
        for (int r4 = 0; r4 < 4; ++r4) {
            int row = row0 + rg * 4 + r4;
            if (row < NN) ((float4*)(hw2 + (size_t)row * DOUT))[tx] = acc[r4];
        }
    }
}

// ---------------- layer 2 aggregation + bias -> out ----------------
__global__ __launch_bounds__(256) void k_agg2(const float* __restrict__ hw2,
                                              const float* __restrict__ dinv,
                                              const int* __restrict__ offs,
                                              const int* __restrict__ esrc,
                                              const float* __restrict__ b2,
                                              float* __restrict__ out) {
    int d = blockIdx.x * 4 + (threadIdx.x >> 6);
    int c = threadIdx.x & 63;
    if (d >= NN || c >= DOUT) return;
    float dd = dinv[d];
    float acc = dd * hw2[(size_t)d * DOUT + c];
    int base = offs[d], end = offs[d + 1];
    int j = base;
    for (; j + 1 < end; j += 2) {
        int s0 = esrc[j], s1 = esrc[j + 1];
        float w0 = dinv[s0], w1 = dinv[s1];
        float v0 = hw2[(size_t)s0 * DOUT + c];
        float v1 = hw2[(size_t)s1 * DOUT + c];
        acc += w0 * v0;
        acc += w1 * v1;
    }
    if (j < end) {
        int s = esrc[j];
        acc += dinv[s] * hw2[(size_t)s * DOUT + c];
    }
    out[(size_t)d * DOUT + c] = dd * acc + b2[c];
}

extern "C" void kernel_launch(void* const* d_in, const int* in_sizes, int n_in,
                              void* d_out, int out_size, void* d_ws, size_t ws_size,
                              hipStream_t stream) {
    const float* x  = (const float*)d_in[0];
    const float* W1 = (const float*)d_in[1];
    const float* b1 = (const float*)d_in[2];
    const float* W2 = (const float*)d_in[3];
    const float* b2 = (const float*)d_in[4];
    const int*   ei = (const int*)d_in[5];
    const int* src = ei;        // edge_index[0]
    const int* dst = ei + EE;   // edge_index[1]
    float* out = (float*)d_out;

    float* ws = (float*)d_ws;
    float* dinv   = ws;                            // NN f32
    int*   cnt    = (int*)(ws + 100000);           // NN
    int*   offs   = (int*)(ws + 200000);           // NN+1
    int*   cursor = (int*)(ws + 300004);           // NN
    int*   bsum   = (int*)(ws + 400004);           // 256
    int*   bsum_s = (int*)(ws + 400260);           // 260 pad
    int*   esrc   = (int*)(ws + 400520);           // EE
    float* xw1    = ws + 1650520;                  // NN*64 (16B aligned)
    float* agg1   = ws + 8050520;                  // NN*64
    float* hw2    = xw1;                           // alias: xw1 dead after k_agg1
    // total: 14,450,520 floats = 57.8 MB

    const int NBLK_SCAN = (NN + 511) / 512;        // 196

    k_zero  <<<(NN + 255) / 256, 256, 0, stream>>>(cnt);
    k_count <<<(EE + 255) / 256, 256, 0, stream>>>(dst, cnt);
    k_dinv  <<<(NN + 255) / 256, 256, 0, stream>>>(cnt, dinv);
    k_scan1 <<<NBLK_SCAN, 512, 0, stream>>>(cnt, offs, bsum);
    k_scan2 <<<1, 256, 0, stream>>>(bsum, bsum_s, NBLK_SCAN);
    k_scan3 <<<(NN + 256) / 256, 256, 0, stream>>>(offs, cursor, bsum_s);
    k_bin   <<<(EE + 255) / 256, 256, 0, stream>>>(src, dst, cursor, esrc);
    k_gemm1 <<<(NN + 63) / 64, 256, 0, stream>>>(x, W1, xw1);
    k_agg1  <<<(NN + 3) / 4, 256, 0, stream>>>(xw1, dinv, offs, esrc, agg1);
    k_gemm2 <<<(NN + 63) / 64, 256, 0, stream>>>(agg1, b1, W2, hw2);
    k_agg2  <<<(NN + 3) / 4, 256, 0, stream>>>(hw2, dinv, offs, esrc, b2, out);
}

// Round 4
// 352.885 us; speedup vs baseline: 2.2030x; 1.3799x over previous
//
#include <hip/hip_runtime.h>

#define NN   100000
#define EE   1250000
#define DIN  128
#define HID  64
#define DOUT 40

#define BN   512                  // nodes per bucket
#define NB   196                  // ceil(NN/BN)
#define CH   4096                 // edges per scatter block (16/thread)

// ---------------- CSR construction (bucketed, write-friendly) ----------------

__global__ __launch_bounds__(256) void kA_zero(int* __restrict__ bucket_cnt) {
    int t = threadIdx.x;
    if (t < NB) bucket_cnt[t] = 0;
}

// histogram edges by dst bucket (dst>>9)
__global__ __launch_bounds__(256) void kA_hist(const int* __restrict__ dst,
                                               int* __restrict__ bucket_cnt) {
    __shared__ int h[NB];
    int t = threadIdx.x;
    for (int i = t; i < NB; i += 256) h[i] = 0;
    __syncthreads();
    int stride = gridDim.x * 256;
    for (int e = blockIdx.x * 256 + t; e < EE; e += stride)
        atomicAdd(&h[dst[e] >> 9], 1);
    __syncthreads();
    for (int i = t; i < NB; i += 256)
        if (h[i]) atomicAdd(&bucket_cnt[i], h[i]);
}

// single-block scan of bucket counts -> bucket_offs, init bucket_cursor
__global__ __launch_bounds__(256) void kA_scanb(const int* __restrict__ bucket_cnt,
                                                int* __restrict__ bucket_offs,
                                                int* __restrict__ bucket_cursor) {
    __shared__ int a[256], b[256];
    int t = threadIdx.x;
    int v = (t < NB) ? bucket_cnt[t] : 0;
    a[t] = v;
    __syncthreads();
    int* s = a; int* d = b;
    for (int off = 1; off < 256; off <<= 1) {
        d[t] = s[t] + ((t >= off) ? s[t - off] : 0);
        __syncthreads();
        int* tmp = s; s = d; d = tmp;
    }
    int incl = s[t];
    if (t < NB) {
        bucket_offs[t]   = incl - v;
        bucket_cursor[t] = incl - v;
    }
    if (t == NB - 1) bucket_offs[NB] = incl;   // == EE
}

// block counting-sort: scatter (src,dst) pairs into bucket segments as
// contiguous per-block runs (coalesced-ish writes, no line ping-pong)
__global__ __launch_bounds__(256) void kA_scatter(const int* __restrict__ src,
                                                  const int* __restrict__ dst,
                                                  int* __restrict__ bucket_cursor,
                                                  int2* __restrict__ ebuf) {
    __shared__ int hist[NB], gbase[NB], rcur[NB];
    int t = threadIdx.x;
    for (int i = t; i < NB; i += 256) { hist[i] = 0; rcur[i] = 0; }
    __syncthreads();
    int e0 = blockIdx.x * CH;
    int es[16], ed[16];
    #pragma unroll
    for (int j = 0; j < 16; ++j) {
        int e = e0 + j * 256 + t;
        bool valid = (e < EE);
        es[j] = valid ? src[e] : 0;
        ed[j] = valid ? dst[e] : -1;
        if (valid) atomicAdd(&hist[ed[j] >> 9], 1);
    }
    __syncthreads();
    for (int i = t; i < NB; i += 256)
        gbase[i] = atomicAdd(&bucket_cursor[i], hist[i]);
    __syncthreads();
    #pragma unroll
    for (int j = 0; j < 16; ++j) {
        if (ed[j] >= 0) {
            int bb = ed[j] >> 9;
            int r = atomicAdd(&rcur[bb], 1);
            ebuf[gbase[bb] + r] = make_int2(es[j], ed[j]);
        }
    }
}

// one block per bucket: exact CSR for its 512 nodes, all writes block-local
__global__ __launch_bounds__(256) void kB_csr(const int2* __restrict__ ebuf,
                                              const int* __restrict__ bucket_offs,
                                              int* __restrict__ offs,
                                              float* __restrict__ dinv,
                                              int* __restrict__ esrc) {
    __shared__ int lcnt[BN], sA[BN], sB[BN], lcur[BN];
    int t = threadIdx.x;
    int b = blockIdx.x;
    int base_node = b * BN;
    lcnt[t] = 0; lcnt[t + 256] = 0;
    __syncthreads();
    int ebeg = bucket_offs[b], eend = bucket_offs[b + 1];
    for (int j = ebeg + t; j < eend; j += 256) {
        int2 p = ebuf[j];
        atomicAdd(&lcnt[p.y - base_node], 1);
    }
    __syncthreads();
    sA[t] = lcnt[t]; sA[t + 256] = lcnt[t + 256];
    __syncthreads();
    int* s = sA; int* d = sB;
    for (int off = 1; off < BN; off <<= 1) {
        d[t] = s[t] + ((t >= off) ? s[t - off] : 0);
        int i2 = t + 256;
        d[i2] = s[i2] + ((i2 >= off) ? s[i2 - off] : 0);
        __syncthreads();
        int* tmp = s; s = d; d = tmp;
    }
    #pragma unroll
    for (int k = 0; k < 2; ++k) {
        int i = t + k * 256;
        int excl = s[i] - lcnt[i];
        lcur[i] = excl;
        int node = base_node + i;
        if (node < NN) {
            offs[node] = ebeg + excl;
            dinv[node] = rsqrtf((float)lcnt[i] + 1.0f);   // +1 self-loop
        }
    }
    if (b == NB - 1 && t == 0) offs[NN] = EE;
    __syncthreads();
    for (int j = ebeg + t; j < eend; j += 256) {
        int2 p = ebuf[j];
        int r = atomicAdd(&lcur[p.y - base_node], 1);
        esrc[ebeg + r] = p.x;   // scattered only within this block's segment
    }
}

// ---------------- layer 1 GEMM: xw1s = dinv * (x @ W1) ----------------
__global__ __launch_bounds__(256) void k_gemm1(const float* __restrict__ x,
                                               const float* __restrict__ W1,
                                               const float* __restrict__ dinv,
                                               float* __restrict__ xw1s) {
    __shared__ float sw[DIN * HID];     // [k][c], 32 KB
    __shared__ float sx[64 * 132];      // rows padded to 132 floats (33 float4)
    int t = threadIdx.x;
    const float4* w4g = (const float4*)W1;
    float4* sw4 = (float4*)sw;
    #pragma unroll
    for (int j = 0; j < 8; ++j) sw4[t + j * 256] = w4g[t + j * 256];
    int row0 = blockIdx.x * 64;
    float4* sx4 = (float4*)sx;
    #pragma unroll
    for (int j = 0; j < 8; ++j) {
        int idx = t + j * 256;          // 2048 float4 = 64 rows x 32
        int r = idx >> 5, k4 = idx & 31;
        int row = row0 + r;
        float4 v = (row < NN) ? ((const float4*)(x + (size_t)row * DIN))[k4]
                              : make_float4(0.f, 0.f, 0.f, 0.f);
        sx4[r * 33 + k4] = v;
    }
    __syncthreads();
    int tx = t & 15;        // channel group: c = tx*4 .. +3
    int rg = t >> 4;        // row group: rows rg*4 .. +3
    float4 acc[4];
    #pragma unroll
    for (int r4 = 0; r4 < 4; ++r4) acc[r4] = make_float4(0.f, 0.f, 0.f, 0.f);
    for (int k0 = 0; k0 < DIN; k0 += 4) {
        float4 w0 = sw4[(k0 + 0) * 16 + tx];
        float4 w1 = sw4[(k0 + 1) * 16 + tx];
        float4 w2 = sw4[(k0 + 2) * 16 + tx];
        float4 w3 = sw4[(k0 + 3) * 16 + tx];
        #pragma unroll
        for (int r4 = 0; r4 < 4; ++r4) {
            float4 xv = sx4[(rg * 4 + r4) * 33 + (k0 >> 2)];
            acc[r4].x += xv.x * w0.x + xv.y * w1.x + xv.z * w2.x + xv.w * w3.x;
            acc[r4].y += xv.x * w0.y + xv.y * w1.y + xv.z * w2.y + xv.w * w3.y;
            acc[r4].z += xv.x * w0.z + xv.y * w1.z + xv.z * w2.z + xv.w * w3.z;
            acc[r4].w += xv.x * w0.w + xv.y * w1.w + xv.z * w2.w + xv.w * w3.w;
        }
    }
    #pragma unroll
    for (int r4 = 0; r4 < 4; ++r4) {
        int row = row0 + rg * 4 + r4;
        if (row < NN) {
            float di = dinv[row];
            float4 o = acc[r4];
            o.x *= di; o.y *= di; o.z *= di; o.w *= di;
            ((float4*)(xw1s + (size_t)row * HID))[tx] = o;
        }
    }
}

// ---------------- layer 1 aggregation (gather, pre-scaled) ----------------
// agg1[d] = dinv[d] * (xw1s[d] + sum_s xw1s[s])   [xw1s already has dinv factor]
__global__ __launch_bounds__(256) void k_agg1(const float* __restrict__ xw1s,
                                              const float* __restrict__ dinv,
                                              const int* __restrict__ offs,
                                              const int* __restrict__ esrc,
                                              float* __restrict__ agg1) {
    int d = blockIdx.x * 4 + (threadIdx.x >> 6);
    if (d >= NN) return;
    int c = threadIdx.x & 63;
    float dd = dinv[d];
    float acc = xw1s[(size_t)d * HID + c];   // self-loop: dinv[d]*xw1[d]
    int jb = offs[d], je = offs[d + 1];
    int j = jb;
    for (; j + 3 < je; j += 4) {
        int s0 = esrc[j], s1 = esrc[j + 1], s2 = esrc[j + 2], s3 = esrc[j + 3];
        float v0 = xw1s[(size_t)s0 * HID + c];
        float v1 = xw1s[(size_t)s1 * HID + c];
        float v2 = xw1s[(size_t)s2 * HID + c];
        float v3 = xw1s[(size_t)s3 * HID + c];
        acc += v0; acc += v1; acc += v2; acc += v3;
    }
    for (; j < je; ++j) acc += xw1s[(size_t)esrc[j] * HID + c];
    agg1[(size_t)d * HID + c] = dd * acc;
}

// ---------------- layer 2 GEMM: hw2s = dinv * (relu(agg1+b1) @ W2) ----------------
__global__ __launch_bounds__(256) void k_gemm2(const float* __restrict__ agg1,
                                               const float* __restrict__ b1,
                                               const float* __restrict__ W2,
                                               const float* __restrict__ dinv,
                                               float* __restrict__ hw2s) {
    __shared__ float sh[64 * 68];        // rows padded to 68 floats (17 float4)
    __shared__ float sw2l[HID * DOUT];   // [k][j], 10 KB
    int t = threadIdx.x;
    const float4* w4g = (const float4*)W2;
    float4* sw4 = (float4*)sw2l;
    for (int i = t; i < HID * DOUT / 4; i += 256) sw4[i] = w4g[i];
    int row0 = blockIdx.x * 64;
    float4* sh4 = (float4*)sh;
    const float4* b14 = (const float4*)b1;
    #pragma unroll
    for (int j = 0; j < 4; ++j) {
        int idx = t + j * 256;           // 1024 float4 = 64 rows x 16
        int r = idx >> 4, c4 = idx & 15;
        int row = row0 + r;
        float4 v = (row < NN) ? ((const float4*)(agg1 + (size_t)row * HID))[c4]
                              : make_float4(0.f, 0.f, 0.f, 0.f);
        float4 bb = b14[c4];
        v.x = fmaxf(v.x + bb.x, 0.f);
        v.y = fmaxf(v.y + bb.y, 0.f);
        v.z = fmaxf(v.z + bb.z, 0.f);
        v.w = fmaxf(v.w + bb.w, 0.f);
        sh4[r * 17 + c4] = v;
    }
    __syncthreads();
    int tx = t & 15;        // 10 active channel groups
    int rg = t >> 4;
    if (tx < 10) {
        float4 acc[4];
        #pragma unroll
        for (int r4 = 0; r4 < 4; ++r4) acc[r4] = make_float4(0.f, 0.f, 0.f, 0.f);
        for (int k0 = 0; k0 < HID; k0 += 4) {
            float4 w0 = sw4[(k0 + 0) * 10 + tx];
            float4 w1 = sw4[(k0 + 1) * 10 + tx];
            float4 w2 = sw4[(k0 + 2) * 10 + tx];
            float4 w3 = sw4[(k0 + 3) * 10 + tx];
            #pragma unroll
            for (int r4 = 0; r4 < 4; ++r4) {
                float4 xv = sh4[(rg * 4 + r4) * 17 + (k0 >> 2)];
                acc[r4].x += xv.x * w0.x + xv.y * w1.x + xv.z * w2.x + xv.w * w3.x;
                acc[r4].y += xv.x * w0.y + xv.y * w1.y + xv.z * w2.y + xv.w * w3.y;
                acc[r4].z += xv.x * w0.z + xv.y * w1.z + xv.z * w2.z + xv.w * w3.z;
                acc[r4].w += xv.x * w0.w + xv.y * w1.w + xv.z * w2.w + xv.w * w3.w;
            }
        }
        #pragma unroll
        for (int r4 = 0; r4 < 4; ++r4) {
            int row = row0 + rg * 4 + r4;
            if (row < NN) {
                float di = dinv[row];
                float4 o = acc[r4];
                o.x *= di; o.y *= di; o.z *= di; o.w *= di;
                ((float4*)(hw2s + (size_t)row * DOUT))[tx] = o;
            }
        }
    }
}

// ---------------- layer 2 aggregation + bias -> out ----------------
// 6 dsts per block, 40 lanes each (240/256 active)
__global__ __launch_bounds__(256) void k_agg2(const float* __restrict__ hw2s,
                                              const float* __restrict__ dinv,
                                              const int* __restrict__ offs,
                                              const int* __restrict__ esrc,
                                              const float* __restrict__ b2,
                                              float* __restrict__ out) {
    int t = threadIdx.x;
    if (t >= 240) return;
    int d = blockIdx.x * 6 + t / 40;
    if (d >= NN) return;
    int c = t % 40;
    float dd = dinv[d];
    float acc = hw2s[(size_t)d * DOUT + c];   // self-loop term (pre-scaled)
    int jb = offs[d], je = offs[d + 1];
    int j = jb;
    for (; j + 3 < je; j += 4) {
        int s0 = esrc[j], s1 = esrc[j + 1], s2 = esrc[j + 2], s3 = esrc[j + 3];
        float v0 = hw2s[(size_t)s0 * DOUT + c];
        float v1 = hw2s[(size_t)s1 * DOUT + c];
        float v2 = hw2s[(size_t)s2 * DOUT + c];
        float v3 = hw2s[(size_t)s3 * DOUT + c];
        acc += v0; acc += v1; acc += v2; acc += v3;
    }
    for (; j < je; ++j) acc += hw2s[(size_t)esrc[j] * DOUT + c];
    out[(size_t)d * DOUT + c] = dd * acc + b2[c];
}

extern "C" void kernel_launch(void* const* d_in, const int* in_sizes, int n_in,
                              void* d_out, int out_size, void* d_ws, size_t ws_size,
                              hipStream_t stream) {
    const float* x  = (const float*)d_in[0];
    const float* W1 = (const float*)d_in[1];
    const float* b1 = (const float*)d_in[2];
    const float* W2 = (const float*)d_in[3];
    const float* b2 = (const float*)d_in[4];
    const int*   ei = (const int*)d_in[5];
    const int* src = ei;        // edge_index[0]
    const int* dst = ei + EE;   // edge_index[1]
    float* out = (float*)d_out;

    float* ws = (float*)d_ws;
    int*   bucket_cnt    = (int*)ws;                    // [0, 256)
    int*   bucket_offs   = (int*)ws + 256;              // [256, 768) (NB+1 used)
    int*   bucket_cursor = (int*)ws + 768;              // [768, 1024)
    int*   offs          = (int*)ws + 1024;             // NN+1 -> [1024, 101025)
    float* dinv          = ws + 101056;                 // NN -> [101056, 201056)
    int*   esrc          = (int*)ws + 201056;           // EE -> [201056, 1451056)
    int2*  ebuf          = (int2*)(ws + 1451056);       // EE pairs -> 2.5M ints
    float* xw1s          = ws + 3951056;                // NN*64
    float* agg1          = ws + 10351056;               // NN*64
    float* hw2s          = xw1s;                        // alias: dead after k_agg1
    // total: 16,751,056 floats = 67.0 MB

    kA_zero    <<<1, 256, 0, stream>>>(bucket_cnt);
    kA_hist    <<<1024, 256, 0, stream>>>(dst, bucket_cnt);
    kA_scanb   <<<1, 256, 0, stream>>>(bucket_cnt, bucket_offs, bucket_cursor);
    kA_scatter <<<(EE + CH - 1) / CH, 256, 0, stream>>>(src, dst, bucket_cursor, ebuf);
    kB_csr     <<<NB, 256, 0, stream>>>(ebuf, bucket_offs, offs, dinv, esrc);
    k_gemm1    <<<(NN + 63) / 64, 256, 0, stream>>>(x, W1, dinv, xw1s);
    k_agg1     <<<(NN + 3) / 4, 256, 0, stream>>>(xw1s, dinv, offs, esrc, agg1);
    k_gemm2    <<<(NN + 63) / 64, 256, 0, stream>>>(agg1, b1, W2, dinv, hw2s);
    k_agg2     <<<(NN + 5) / 6, 256, 0, stream>>>(hw2s, dinv, offs, esrc, b2, out);
}

// Round 6
// 344.172 us; speedup vs baseline: 2.2587x; 1.0253x over previous
//
#include <hip/hip_runtime.h>
#include <hip/hip_fp16.h>

#define NN   100000
#define EE   1250000
#define DIN  128
#define HID  64
#define DOUT 40

#define BN   512                  // nodes per bucket
#define NB   196                  // ceil(NN/BN)
#define CH   4096                 // edges per scatter block (16/thread)

// ---------------- CSR construction (bucketed, write-friendly) ----------------

__global__ __launch_bounds__(256) void kA_zero(int* __restrict__ bucket_cnt) {
    int t = threadIdx.x;
    if (t < NB) bucket_cnt[t] = 0;
}

// histogram edges by dst bucket (dst>>9)
__global__ __launch_bounds__(256) void kA_hist(const int* __restrict__ dst,
                                               int* __restrict__ bucket_cnt) {
    __shared__ int h[NB];
    int t = threadIdx.x;
    for (int i = t; i < NB; i += 256) h[i] = 0;
    __syncthreads();
    int stride = gridDim.x * 256;
    for (int e = blockIdx.x * 256 + t; e < EE; e += stride)
        atomicAdd(&h[dst[e] >> 9], 1);
    __syncthreads();
    for (int i = t; i < NB; i += 256)
        if (h[i]) atomicAdd(&bucket_cnt[i], h[i]);
}

// single-block scan of bucket counts -> bucket_offs, init bucket_cursor
__global__ __launch_bounds__(256) void kA_scanb(const int* __restrict__ bucket_cnt,
                                                int* __restrict__ bucket_offs,
                                                int* __restrict__ bucket_cursor) {
    __shared__ int a[256], b[256];
    int t = threadIdx.x;
    int v = (t < NB) ? bucket_cnt[t] : 0;
    a[t] = v;
    __syncthreads();
    int* s = a; int* d = b;
    for (int off = 1; off < 256; off <<= 1) {
        d[t] = s[t] + ((t >= off) ? s[t - off] : 0);
        __syncthreads();
        int* tmp = s; s = d; d = tmp;
    }
    int incl = s[t];
    if (t < NB) {
        bucket_offs[t]   = incl - v;
        bucket_cursor[t] = incl - v;
    }
    if (t == NB - 1) bucket_offs[NB] = incl;   // == EE
}

// block counting-sort: scatter packed (src<<9|local_dst) into bucket segments
__global__ __launch_bounds__(256) void kA_scatter(const int* __restrict__ src,
                                                  const int* __restrict__ dst,
                                                  int* __restrict__ bucket_cursor,
                                                  int* __restrict__ ebuf) {
    __shared__ int hist[NB], gbase[NB], rcur[NB];
    int t = threadIdx.x;
    for (int i = t; i < NB; i += 256) { hist[i] = 0; rcur[i] = 0; }
    __syncthreads();
    int e0 = blockIdx.x * CH;
    int ep[16], eb[16];
    #pragma unroll
    for (int j = 0; j < 16; ++j) {
        int e = e0 + j * 256 + t;
        bool valid = (e < EE);
        if (valid) {
            int dd_ = dst[e];
            ep[j] = (src[e] << 9) | (dd_ & 511);
            eb[j] = dd_ >> 9;
            atomicAdd(&hist[eb[j]], 1);
        } else {
            ep[j] = 0; eb[j] = -1;
        }
    }
    __syncthreads();
    for (int i = t; i < NB; i += 256)
        gbase[i] = atomicAdd(&bucket_cursor[i], hist[i]);
    __syncthreads();
    #pragma unroll
    for (int j = 0; j < 16; ++j) {
        if (eb[j] >= 0) {
            int r = atomicAdd(&rcur[eb[j]], 1);
            ebuf[gbase[eb[j]] + r] = ep[j];
        }
    }
}

// one block per bucket: exact CSR for its 512 nodes, all writes block-local
__global__ __launch_bounds__(256) void kB_csr(const int* __restrict__ ebuf,
                                              const int* __restrict__ bucket_offs,
                                              int* __restrict__ offs,
                                              float* __restrict__ dinv,
                                              int* __restrict__ esrc) {
    __shared__ int lcnt[BN], sA[BN], sB[BN], lcur[BN];
    int t = threadIdx.x;
    int b = blockIdx.x;
    lcnt[t] = 0; lcnt[t + 256] = 0;
    __syncthreads();
    int ebeg = bucket_offs[b], eend = bucket_offs[b + 1];
    for (int j = ebeg + t; j < eend; j += 256)
        atomicAdd(&lcnt[ebuf[j] & 511], 1);
    __syncthreads();
    sA[t] = lcnt[t]; sA[t + 256] = lcnt[t + 256];
    __syncthreads();
    int* s = sA; int* d = sB;
    for (int off = 1; off < BN; off <<= 1) {
        d[t] = s[t] + ((t >= off) ? s[t - off] : 0);
        int i2 = t + 256;
        d[i2] = s[i2] + ((i2 >= off) ? s[i2 - off] : 0);
        __syncthreads();
        int* tmp = s; s = d; d = tmp;
    }
    int base_node = b * BN;
    #pragma unroll
    for (int k = 0; k < 2; ++k) {
        int i = t + k * 256;
        int excl = s[i] - lcnt[i];
        lcur[i] = excl;
        int node = base_node + i;
        if (node < NN) {
            offs[node] = ebeg + excl;
            dinv[node] = rsqrtf((float)lcnt[i] + 1.0f);   // +1 self-loop
        }
    }
    if (b == NB - 1 && t == 0) offs[NN] = EE;
    __syncthreads();
    for (int j = ebeg + t; j < eend; j += 256) {
        int p = ebuf[j];
        int r = atomicAdd(&lcur[p & 511], 1);
        esrc[ebeg + r] = p >> 9;   // scattered only within this block's segment
    }
}

// ---------------- layer 1 GEMM: xw1h = fp16(dinv * (x @ W1)) ----------------
__global__ __launch_bounds__(256) void k_gemm1(const float* __restrict__ x,
                                               const float* __restrict__ W1,
                                               const float* __restrict__ dinv,
                                               __half* __restrict__ xw1h) {
    __shared__ float sw[DIN * HID];     // [k][c], 32 KB
    __shared__ float sx[64 * 132];      // rows padded to 132 floats (33 float4)
    int t = threadIdx.x;
    const float4* w4g = (const float4*)W1;
    float4* sw4 = (float4*)sw;
    #pragma unroll
    for (int j = 0; j < 8; ++j) sw4[t + j * 256] = w4g[t + j * 256];
    int row0 = blockIdx.x * 64;
    float4* sx4 = (float4*)sx;
    #pragma unroll
    for (int j = 0; j < 8; ++j) {
        int idx = t + j * 256;          // 2048 float4 = 64 rows x 32
        int r = idx >> 5, k4 = idx & 31;
        int row = row0 + r;
        float4 v = (row < NN) ? ((const float4*)(x + (size_t)row * DIN))[k4]
                              : make_float4(0.f, 0.f, 0.f, 0.f);
        sx4[r * 33 + k4] = v;
    }
    __syncthreads();
    int tx = t & 15;        // channel group: c = tx*4 .. +3
    int rg = t >> 4;        // row group: rows rg*4 .. +3
    float4 acc[4];
    #pragma unroll
    for (int r4 = 0; r4 < 4; ++r4) acc[r4] = make_float4(0.f, 0.f, 0.f, 0.f);
    for (int k0 = 0; k0 < DIN; k0 += 4) {
        float4 w0 = sw4[(k0 + 0) * 16 + tx];
        float4 w1 = sw4[(k0 + 1) * 16 + tx];
        float4 w2 = sw4[(k0 + 2) * 16 + tx];
        float4 w3 = sw4[(k0 + 3) * 16 + tx];
        #pragma unroll
        for (int r4 = 0; r4 < 4; ++r4) {
            float4 xv = sx4[(rg * 4 + r4) * 33 + (k0 >> 2)];
            acc[r4].x += xv.x * w0.x + xv.y * w1.x + xv.z * w2.x + xv.w * w3.x;
            acc[r4].y += xv.x * w0.y + xv.y * w1.y + xv.z * w2.y + xv.w * w3.y;
            acc[r4].z += xv.x * w0.z + xv.y * w1.z + xv.z * w2.z + xv.w * w3.z;
            acc[r4].w += xv.x * w0.w + xv.y * w1.w + xv.z * w2.w + xv.w * w3.w;
        }
    }
    #pragma unroll
    for (int r4 = 0; r4 < 4; ++r4) {
        int row = row0 + rg * 4 + r4;
        if (row < NN) {
            float di = dinv[row];
            float4 o = acc[r4];
            float2 st;
            ((__half2*)&st)[0] = __floats2half2_rn(o.x * di, o.y * di);
            ((__half2*)&st)[1] = __floats2half2_rn(o.z * di, o.w * di);
            ((float2*)(xw1h + (size_t)row * HID))[tx] = st;
        }
    }
}

// ---------------- layer 1 aggregation (gather, fp16 table) ----------------
__global__ __launch_bounds__(256) void k_agg1(const __half* __restrict__ xw1h,
                                              const float* __restrict__ dinv,
                                              const int* __restrict__ offs,
                                              const int* __restrict__ esrc,
                                              float* __restrict__ agg1) {
    int d = blockIdx.x * 4 + (threadIdx.x >> 6);
    if (d >= NN) return;
    int c = threadIdx.x & 63;
    float dd = dinv[d];
    float acc = __half2float(xw1h[(size_t)d * HID + c]);   // self-loop term
    int jb = offs[d], je = offs[d + 1];
    int j = jb;
    for (; j + 7 < je; j += 8) {
        int s0 = esrc[j],     s1 = esrc[j + 1], s2 = esrc[j + 2], s3 = esrc[j + 3];
        int s4 = esrc[j + 4], s5 = esrc[j + 5], s6 = esrc[j + 6], s7 = esrc[j + 7];
        float v0 = __half2float(xw1h[(size_t)s0 * HID + c]);
        float v1 = __half2float(xw1h[(size_t)s1 * HID + c]);
        float v2 = __half2float(xw1h[(size_t)s2 * HID + c]);
        float v3 = __half2float(xw1h[(size_t)s3 * HID + c]);
        float v4 = __half2float(xw1h[(size_t)s4 * HID + c]);
        float v5 = __half2float(xw1h[(size_t)s5 * HID + c]);
        float v6 = __half2float(xw1h[(size_t)s6 * HID + c]);
        float v7 = __half2float(xw1h[(size_t)s7 * HID + c]);
        acc += v0; acc += v1; acc += v2; acc += v3;
        acc += v4; acc += v5; acc += v6; acc += v7;
    }
    for (; j < je; ++j)
        acc += __half2float(xw1h[(size_t)esrc[j] * HID + c]);
    agg1[(size_t)d * HID + c] = dd * acc;
}

// ---------------- layer 2 GEMM: hw2h = fp16(dinv * (relu(agg1+b1) @ W2)) ----------------
__global__ __launch_bounds__(256) void k_gemm2(const float* __restrict__ agg1,
                                               const float* __restrict__ b1,
                                               const float* __restrict__ W2,
                                               const float* __restrict__ dinv,
                                               __half* __restrict__ hw2h) {
    __shared__ float sh[64 * 68];        // rows padded to 68 floats (17 float4)
    __shared__ float sw2l[HID * DOUT];   // [k][j], 10 KB
    int t = threadIdx.x;
    const float4* w4g = (const float4*)W2;
    float4* sw4 = (float4*)sw2l;
    for (int i = t; i < HID * DOUT / 4; i += 256) sw4[i] = w4g[i];
    int row0 = blockIdx.x * 64;
    float4* sh4 = (float4*)sh;
    const float4* b14 = (const float4*)b1;
    #pragma unroll
    for (int j = 0; j < 4; ++j) {
        int idx = t + j * 256;           // 1024 float4 = 64 rows x 16
        int r = idx >> 4, c4 = idx & 15;
        int row = row0 + r;
        float4 v = (row < NN) ? ((const float4*)(agg1 + (size_t)row * HID))[c4]
                              : make_float4(0.f, 0.f, 0.f, 0.f);
        float4 bb = b14[c4];
        v.x = fmaxf(v.x + bb.x, 0.f);
        v.y = fmaxf(v.y + bb.y, 0.f);
        v.z = fmaxf(v.z + bb.z, 0.f);
        v.w = fmaxf(v.w + bb.w, 0.f);
        sh4[r * 17 + c4] = v;
    }
    __syncthreads();
    int tx = t & 15;        // 10 active channel groups
    int rg = t >> 4;
    if (tx < 10) {
        float4 acc[4];
        #pragma unroll
        for (int r4 = 0; r4 < 4; ++r4) acc[r4] = make_float4(0.f, 0.f, 0.f, 0.f);
        for (int k0 = 0; k0 < HID; k0 += 4) {
            float4 w0 = sw4[(k0 + 0) * 10 + tx];
            float4 w1 = sw4[(k0 + 1) * 10 + tx];
            float4 w2 = sw4[(k0 + 2) * 10 + tx];
            float4 w3 = sw4[(k0 + 3) * 10 + tx];
            #pragma unroll
            for (int r4 = 0; r4 < 4; ++r4) {
                float4 xv = sh4[(rg * 4 + r4) * 17 + (k0 >> 2)];
                acc[r4].x += xv.x * w0.x + xv.y * w1.x + xv.z * w2.x + xv.w * w3.x;
                acc[r4].y += xv.x * w0.y + xv.y * w1.y + xv.z * w2.y + xv.w * w3.y;
                acc[r4].z += xv.x * w0.z + xv.y * w1.z + xv.z * w2.z + xv.w * w3.z;
                acc[r4].w += xv.x * w0.w + xv.y * w1.w + xv.z * w2.w + xv.w * w3.w;
            }
        }
        #pragma unroll
        for (int r4 = 0; r4 < 4; ++r4) {
            int row = row0 + rg * 4 + r4;
            if (row < NN) {
                float di = dinv[row];
                float4 o = acc[r4];
                float2 st;
                ((__half2*)&st)[0] = __floats2half2_rn(o.x * di, o.y * di);
                ((__half2*)&st)[1] = __floats2half2_rn(o.z * di, o.w * di);
                ((float2*)(hw2h + (size_t)row * DOUT))[tx] = st;
            }
        }
    }
}

// ---------------- layer 2 aggregation + bias -> out ----------------
// 6 dsts per block, 40 lanes each (240/256 active)
__global__ __launch_bounds__(256) void k_agg2(const __half* __restrict__ hw2h,
                                              const float* __restrict__ dinv,
                                              const int* __restrict__ offs,
                                              const int* __restrict__ esrc,
                                              const float* __restrict__ b2,
                                              float* __restrict__ out) {
    int t = threadIdx.x;
    if (t >= 240) return;
    int d = blockIdx.x * 6 + t / 40;
    if (d >= NN) return;
    int c = t % 40;
    float dd = dinv[d];
    float acc = __half2float(hw2h[(size_t)d * DOUT + c]);   // self-loop term
    int jb = offs[d], je = offs[d + 1];
    int j = jb;
    for (; j + 7 < je; j += 8) {
        int s0 = esrc[j],     s1 = esrc[j + 1], s2 = esrc[j + 2], s3 = esrc[j + 3];
        int s4 = esrc[j + 4], s5 = esrc[j + 5], s6 = esrc[j + 6], s7 = esrc[j + 7];
        float v0 = __half2float(hw2h[(size_t)s0 * DOUT + c]);
        float v1 = __half2float(hw2h[(size_t)s1 * DOUT + c]);
        float v2 = __half2float(hw2h[(size_t)s2 * DOUT + c]);
        float v3 = __half2float(hw2h[(size_t)s3 * DOUT + c]);
        float v4 = __half2float(hw2h[(size_t)s4 * DOUT + c]);
        float v5 = __half2float(hw2h[(size_t)s5 * DOUT + c]);
        float v6 = __half2float(hw2h[(size_t)s6 * DOUT + c]);
        float v7 = __half2float(hw2h[(size_t)s7 * DOUT + c]);
        acc += v0; acc += v1; acc += v2; acc += v3;
        acc += v4; acc += v5; acc += v6; acc += v7;
    }
    for (; j < je; ++j)
        acc += __half2float(hw2h[(size_t)esrc[j] * DOUT + c]);
    out[(size_t)d * DOUT + c] = dd * acc + b2[c];
}

extern "C" void kernel_launch(void* const* d_in, const int* in_sizes, int n_in,
                              void* d_out, int out_size, void* d_ws, size_t ws_size,
                              hipStream_t stream) {
    const float* x  = (const float*)d_in[0];
    const float* W1 = (const float*)d_in[1];
    const float* b1 = (const float*)d_in[2];
    const float* W2 = (const float*)d_in[3];
    const float* b2 = (const float*)d_in[4];
    const int*   ei = (const int*)d_in[5];
    const int* src = ei;        // edge_index[0]
    const int* dst = ei + EE;   // edge_index[1]
    float* out = (float*)d_out;

    float* ws = (float*)d_ws;
    int*    bucket_cnt    = (int*)ws;                   // [0,256)
    int*    bucket_offs   = (int*)ws + 256;             // [256,512) NB+1 used
    int*    bucket_cursor = (int*)ws + 512;             // [512,768)
    int*    offs          = (int*)ws + 1024;            // NN+1
    float*  dinv          = ws + 101056;                // NN
    int*    esrc          = (int*)ws + 201056;          // EE
    int*    ebuf          = (int*)ws + 1451056;         // EE packed
    __half* xw1h          = (__half*)(ws + 2701056);    // NN*64 halves = 3.2M floats -> [2701056, 5901056)
    float*  agg1          = ws + 5901056;               // NN*64 f32 -> [5901056, 12301056)
    __half* hw2h          = xw1h;                       // alias: xw1h dead after k_agg1; hw2h is NN*40 halves (fits)
    // total: 12,301,056 floats = 49.2 MB

    kA_zero    <<<1, 256, 0, stream>>>(bucket_cnt);
    kA_hist    <<<1024, 256, 0, stream>>>(dst, bucket_cnt);
    kA_scanb   <<<1, 256, 0, stream>>>(bucket_cnt, bucket_offs, bucket_cursor);
    kA_scatter <<<(EE + CH - 1) / CH, 256, 0, stream>>>(src, dst, bucket_cursor, ebuf);
    kB_csr     <<<NB, 256, 0, stream>>>(ebuf, bucket_offs, offs, dinv, esrc);
    k_gemm1    <<<(NN + 63) / 64, 256, 0, stream>>>(x, W1, dinv, xw1h);
    k_agg1     <<<(NN + 3) / 4, 256, 0, stream>>>(xw1h, dinv, offs, esrc, agg1);
    k_gemm2    <<<(NN + 63) / 64, 256, 0, stream>>>(agg1, b1, W2, dinv, hw2h);
    k_agg2     <<<(NN + 5) / 6, 256, 0, stream>>>(hw2h, dinv, offs, esrc, b2, out);
}

// Round 7
// 310.160 us; speedup vs baseline: 2.5064x; 1.1097x over previous
//
#include <hip/hip_runtime.h>
#include <hip/hip_fp16.h>

#define NN   100000
#define EE   1250000
#define DIN  128
#define HID  64
#define DOUT 40

#define BN   512                  // nodes per bucket
#define NB   196                  // ceil(NN/BN)
#define CH   4096                 // edges per scatter block (16/thread)

struct __align__(8) h4 { __half2 a, b; };   // 4 halves, one dwordx2 load

// ---------------- CSR construction (bucketed, write-friendly) ----------------

__global__ __launch_bounds__(256) void kA_zero(int* __restrict__ bucket_cnt) {
    int t = threadIdx.x;
    if (t < NB) bucket_cnt[t] = 0;
}

// histogram edges by dst bucket (dst>>9)
__global__ __launch_bounds__(256) void kA_hist(const int* __restrict__ dst,
                                               int* __restrict__ bucket_cnt) {
    __shared__ int h[NB];
    int t = threadIdx.x;
    for (int i = t; i < NB; i += 256) h[i] = 0;
    __syncthreads();
    int stride = gridDim.x * 256;
    for (int e = blockIdx.x * 256 + t; e < EE; e += stride)
        atomicAdd(&h[dst[e] >> 9], 1);
    __syncthreads();
    for (int i = t; i < NB; i += 256)
        if (h[i]) atomicAdd(&bucket_cnt[i], h[i]);
}

// single-block scan of bucket counts -> bucket_offs, init bucket_cursor
__global__ __launch_bounds__(256) void kA_scanb(const int* __restrict__ bucket_cnt,
                                                int* __restrict__ bucket_offs,
                                                int* __restrict__ bucket_cursor) {
    __shared__ int a[256], b[256];
    int t = threadIdx.x;
    int v = (t < NB) ? bucket_cnt[t] : 0;
    a[t] = v;
    __syncthreads();
    int* s = a; int* d = b;
    for (int off = 1; off < 256; off <<= 1) {
        d[t] = s[t] + ((t >= off) ? s[t - off] : 0);
        __syncthreads();
        int* tmp = s; s = d; d = tmp;
    }
    int incl = s[t];
    if (t < NB) {
        bucket_offs[t]   = incl - v;
        bucket_cursor[t] = incl - v;
    }
    if (t == NB - 1) bucket_offs[NB] = incl;   // == EE
}

// block counting-sort: scatter packed (src<<9|local_dst) into bucket segments
__global__ __launch_bounds__(256) void kA_scatter(const int* __restrict__ src,
                                                  const int* __restrict__ dst,
                                                  int* __restrict__ bucket_cursor,
                                                  int* __restrict__ ebuf) {
    __shared__ int hist[NB], gbase[NB], rcur[NB];
    int t = threadIdx.x;
    for (int i = t; i < NB; i += 256) { hist[i] = 0; rcur[i] = 0; }
    __syncthreads();
    int e0 = blockIdx.x * CH;
    int ep[16], eb[16];
    #pragma unroll
    for (int j = 0; j < 16; ++j) {
        int e = e0 + j * 256 + t;
        bool valid = (e < EE);
        if (valid) {
            int dd_ = dst[e];
            ep[j] = (src[e] << 9) | (dd_ & 511);
            eb[j] = dd_ >> 9;
            atomicAdd(&hist[eb[j]], 1);
        } else {
            ep[j] = 0; eb[j] = -1;
        }
    }
    __syncthreads();
    for (int i = t; i < NB; i += 256)
        gbase[i] = atomicAdd(&bucket_cursor[i], hist[i]);
    __syncthreads();
    #pragma unroll
    for (int j = 0; j < 16; ++j) {
        if (eb[j] >= 0) {
            int r = atomicAdd(&rcur[eb[j]], 1);
            ebuf[gbase[eb[j]] + r] = ep[j];
        }
    }
}

// one block per bucket: exact CSR for its 512 nodes, all writes block-local
__global__ __launch_bounds__(256) void kB_csr(const int* __restrict__ ebuf,
                                              const int* __restrict__ bucket_offs,
                                              int* __restrict__ offs,
                                              float* __restrict__ dinv,
                                              int* __restrict__ esrc) {
    __shared__ int lcnt[BN], sA[BN], sB[BN], lcur[BN];
    int t = threadIdx.x;
    int b = blockIdx.x;
    lcnt[t] = 0; lcnt[t + 256] = 0;
    __syncthreads();
    int ebeg = bucket_offs[b], eend = bucket_offs[b + 1];
    for (int j = ebeg + t; j < eend; j += 256)
        atomicAdd(&lcnt[ebuf[j] & 511], 1);
    __syncthreads();
    sA[t] = lcnt[t]; sA[t + 256] = lcnt[t + 256];
    __syncthreads();
    int* s = sA; int* d = sB;
    for (int off = 1; off < BN; off <<= 1) {
        d[t] = s[t] + ((t >= off) ? s[t - off] : 0);
        int i2 = t + 256;
        d[i2] = s[i2] + ((i2 >= off) ? s[i2 - off] : 0);
        __syncthreads();
        int* tmp = s; s = d; d = tmp;
    }
    int base_node = b * BN;
    #pragma unroll
    for (int k = 0; k < 2; ++k) {
        int i = t + k * 256;
        int excl = s[i] - lcnt[i];
        lcur[i] = excl;
        int node = base_node + i;
        if (node < NN) {
            offs[node] = ebeg + excl;
            dinv[node] = rsqrtf((float)lcnt[i] + 1.0f);   // +1 self-loop
        }
    }
    if (b == NB - 1 && t == 0) offs[NN] = EE;
    __syncthreads();
    for (int j = ebeg + t; j < eend; j += 256) {
        int p = ebuf[j];
        int r = atomicAdd(&lcur[p & 511], 1);
        esrc[ebeg + r] = p >> 9;   // scattered only within this block's segment
    }
}

// ---------------- layer 1 GEMM: xw1h = fp16(dinv * (x @ W1)) ----------------
__global__ __launch_bounds__(256) void k_gemm1(const float* __restrict__ x,
                                               const float* __restrict__ W1,
                                               const float* __restrict__ dinv,
                                               __half* __restrict__ xw1h) {
    __shared__ float sw[DIN * HID];     // [k][c], 32 KB
    __shared__ float sx[64 * 132];      // rows padded to 132 floats (33 float4)
    int t = threadIdx.x;
    const float4* w4g = (const float4*)W1;
    float4* sw4 = (float4*)sw;
    #pragma unroll
    for (int j = 0; j < 8; ++j) sw4[t + j * 256] = w4g[t + j * 256];
    int row0 = blockIdx.x * 64;
    float4* sx4 = (float4*)sx;
    #pragma unroll
    for (int j = 0; j < 8; ++j) {
        int idx = t + j * 256;          // 2048 float4 = 64 rows x 32
        int r = idx >> 5, k4 = idx & 31;
        int row = row0 + r;
        float4 v = (row < NN) ? ((const float4*)(x + (size_t)row * DIN))[k4]
                              : make_float4(0.f, 0.f, 0.f, 0.f);
        sx4[r * 33 + k4] = v;
    }
    __syncthreads();
    int tx = t & 15;        // channel group: c = tx*4 .. +3
    int rg = t >> 4;        // row group: rows rg*4 .. +3
    float4 acc[4];
    #pragma unroll
    for (int r4 = 0; r4 < 4; ++r4) acc[r4] = make_float4(0.f, 0.f, 0.f, 0.f);
    for (int k0 = 0; k0 < DIN; k0 += 4) {
        float4 w0 = sw4[(k0 + 0) * 16 + tx];
        float4 w1 = sw4[(k0 + 1) * 16 + tx];
        float4 w2 = sw4[(k0 + 2) * 16 + tx];
        float4 w3 = sw4[(k0 + 3) * 16 + tx];
        #pragma unroll
        for (int r4 = 0; r4 < 4; ++r4) {
            float4 xv = sx4[(rg * 4 + r4) * 33 + (k0 >> 2)];
            acc[r4].x += xv.x * w0.x + xv.y * w1.x + xv.z * w2.x + xv.w * w3.x;
            acc[r4].y += xv.x * w0.y + xv.y * w1.y + xv.z * w2.y + xv.w * w3.y;
            acc[r4].z += xv.x * w0.z + xv.y * w1.z + xv.z * w2.z + xv.w * w3.z;
            acc[r4].w += xv.x * w0.w + xv.y * w1.w + xv.z * w2.w + xv.w * w3.w;
        }
    }
    #pragma unroll
    for (int r4 = 0; r4 < 4; ++r4) {
        int row = row0 + rg * 4 + r4;
        if (row < NN) {
            float di = dinv[row];
            float4 o = acc[r4];
            float2 st;
            ((__half2*)&st)[0] = __floats2half2_rn(o.x * di, o.y * di);
            ((__half2*)&st)[1] = __floats2half2_rn(o.z * di, o.w * di);
            ((float2*)(xw1h + (size_t)row * HID))[tx] = st;
        }
    }
}

// ---------------- layer 1 aggregation: 4 edges/wave, 8B loads ----------------
// wave per dst. lane = 16*eg + q; group eg handles edges jb+eg, jb+eg+4, ...
// lane loads h4 (4 ch) -> one wave load instr gathers 4 rows x 128B.
__global__ __launch_bounds__(256) void k_agg1(const __half* __restrict__ xw1h,
                                              const float* __restrict__ dinv,
                                              const int* __restrict__ offs,
                                              const int* __restrict__ esrc,
                                              float* __restrict__ agg1) {
    int d = blockIdx.x * 4 + (threadIdx.x >> 6);
    if (d >= NN) return;
    int l  = threadIdx.x & 63;
    int eg = l >> 4;                    // edge group 0..3
    int q  = l & 15;                    // h4 index within row (16 h4 = 64 ch)
    const h4* table = (const h4*)xw1h;
    float4 acc = make_float4(0.f, 0.f, 0.f, 0.f);
    if (eg == 0) {                      // self-loop term counted once
        h4 v = table[(unsigned)d * 16u + q];
        float2 f0 = __half22float2(v.a), f1 = __half22float2(v.b);
        acc = make_float4(f0.x, f0.y, f1.x, f1.y);
    }
    int jb = offs[d], je = offs[d + 1];
    int j = jb + eg;
    for (; j + 4 < je; j += 8) {        // 2 rows in flight per group = 8 per wave
        int s0 = esrc[j];
        int s1 = esrc[j + 4];
        h4 v0 = table[(unsigned)s0 * 16u + q];
        h4 v1 = table[(unsigned)s1 * 16u + q];
        float2 a0 = __half22float2(v0.a), b0 = __half22float2(v0.b);
        float2 a1 = __half22float2(v1.a), b1 = __half22float2(v1.b);
        acc.x += a0.x + a1.x; acc.y += a0.y + a1.y;
        acc.z += b0.x + b1.x; acc.w += b0.y + b1.y;
    }
    if (j < je) {
        int s = esrc[j];
        h4 v = table[(unsigned)s * 16u + q];
        float2 a = __half22float2(v.a), b = __half22float2(v.b);
        acc.x += a.x; acc.y += a.y; acc.z += b.x; acc.w += b.y;
    }
    // reduce across the 4 edge groups (lanes q, q+16, q+32, q+48)
    acc.x += __shfl_xor(acc.x, 16); acc.y += __shfl_xor(acc.y, 16);
    acc.z += __shfl_xor(acc.z, 16); acc.w += __shfl_xor(acc.w, 16);
    acc.x += __shfl_xor(acc.x, 32); acc.y += __shfl_xor(acc.y, 32);
    acc.z += __shfl_xor(acc.z, 32); acc.w += __shfl_xor(acc.w, 32);
    if (l < 16) {
        float dd = dinv[d];
        ((float4*)(agg1 + (size_t)d * HID))[q] =
            make_float4(dd * acc.x, dd * acc.y, dd * acc.z, dd * acc.w);
    }
}

// ---------------- layer 2 GEMM: hw2h = fp16(dinv * (relu(agg1+b1) @ W2)) ----------------
__global__ __launch_bounds__(256) void k_gemm2(const float* __restrict__ agg1,
                                               const float* __restrict__ b1,
                                               const float* __restrict__ W2,
                                               const float* __restrict__ dinv,
                                               __half* __restrict__ hw2h) {
    __shared__ float sh[64 * 68];        // rows padded to 68 floats (17 float4)
    __shared__ float sw2l[HID * DOUT];   // [k][j], 10 KB
    int t = threadIdx.x;
    const float4* w4g = (const float4*)W2;
    float4* sw4 = (float4*)sw2l;
    for (int i = t; i < HID * DOUT / 4; i += 256) sw4[i] = w4g[i];
    int row0 = blockIdx.x * 64;
    float4* sh4 = (float4*)sh;
    const float4* b14 = (const float4*)b1;
    #pragma unroll
    for (int j = 0; j < 4; ++j) {
        int idx = t + j * 256;           // 1024 float4 = 64 rows x 16
        int r = idx >> 4, c4 = idx & 15;
        int row = row0 + r;
        float4 v = (row < NN) ? ((const float4*)(agg1 + (size_t)row * HID))[c4]
                              : make_float4(0.f, 0.f, 0.f, 0.f);
        float4 bb = b14[c4];
        v.x = fmaxf(v.x + bb.x, 0.f);
        v.y = fmaxf(v.y + bb.y, 0.f);
        v.z = fmaxf(v.z + bb.z, 0.f);
        v.w = fmaxf(v.w + bb.w, 0.f);
        sh4[r * 17 + c4] = v;
    }
    __syncthreads();
    int tx = t & 15;        // 10 active channel groups
    int rg = t >> 4;
    if (tx < 10) {
        float4 acc[4];
        #pragma unroll
        for (int r4 = 0; r4 < 4; ++r4) acc[r4] = make_float4(0.f, 0.f, 0.f, 0.f);
        for (int k0 = 0; k0 < HID; k0 += 4) {
            float4 w0 = sw4[(k0 + 0) * 10 + tx];
            float4 w1 = sw4[(k0 + 1) * 10 + tx];
            float4 w2 = sw4[(k0 + 2) * 10 + tx];
            float4 w3 = sw4[(k0 + 3) * 10 + tx];
            #pragma unroll
            for (int r4 = 0; r4 < 4; ++r4) {
                float4 xv = sh4[(rg * 4 + r4) * 17 + (k0 >> 2)];
                acc[r4].x += xv.x * w0.x + xv.y * w1.x + xv.z * w2.x + xv.w * w3.x;
                acc[r4].y += xv.x * w0.y + xv.y * w1.y + xv.z * w2.y + xv.w * w3.y;
                acc[r4].z += xv.x * w0.z + xv.y * w1.z + xv.z * w2.z + xv.w * w3.z;
                acc[r4].w += xv.x * w0.w + xv.y * w1.w + xv.z * w2.w + xv.w * w3.w;
            }
        }
        #pragma unroll
        for (int r4 = 0; r4 < 4; ++r4) {
            int row = row0 + rg * 4 + r4;
            if (row < NN) {
                float di = dinv[row];
                float4 o = acc[r4];
                float2 st;
                ((__half2*)&st)[0] = __floats2half2_rn(o.x * di, o.y * di);
                ((__half2*)&st)[1] = __floats2half2_rn(o.z * di, o.w * di);
                ((float2*)(hw2h + (size_t)row * DOUT))[tx] = st;
            }
        }
    }
}

// ---------------- layer 2 aggregation: 10 lanes/row, 8B loads ----------------
// 24 dsts per 240-thread block; group of 10 lanes walks its dst's edge list.
__global__ __launch_bounds__(256) void k_agg2(const __half* __restrict__ hw2h,
                                              const float* __restrict__ dinv,
                                              const int* __restrict__ offs,
                                              const int* __restrict__ esrc,
                                              const float* __restrict__ b2,
                                              float* __restrict__ out) {
    int t = threadIdx.x;
    if (t >= 240) return;
    int g = t / 10;                     // dst slot 0..23
    int q = t % 10;                     // h4 index within row (10 h4 = 40 ch)
    int d = blockIdx.x * 24 + g;
    if (d >= NN) return;
    const h4* table = (const h4*)hw2h;
    h4 v = table[(unsigned)d * 10u + q];   // self-loop term
    float2 f0 = __half22float2(v.a), f1 = __half22float2(v.b);
    float4 acc = make_float4(f0.x, f0.y, f1.x, f1.y);
    int jb = offs[d], je = offs[d + 1];
    int j = jb;
    for (; j + 3 < je; j += 4) {        // 4 rows in flight per group
        int s0 = esrc[j],     s1 = esrc[j + 1];
        int s2 = esrc[j + 2], s3 = esrc[j + 3];
        h4 v0 = table[(unsigned)s0 * 10u + q];
        h4 v1 = table[(unsigned)s1 * 10u + q];
        h4 v2 = table[(unsigned)s2 * 10u + q];
        h4 v3 = table[(unsigned)s3 * 10u + q];
        float2 a0 = __half22float2(v0.a), c0 = __half22float2(v0.b);
        float2 a1 = __half22float2(v1.a), c1 = __half22float2(v1.b);
        float2 a2 = __half22float2(v2.a), c2 = __half22float2(v2.b);
        float2 a3 = __half22float2(v3.a), c3 = __half22float2(v3.b);
        acc.x += (a0.x + a1.x) + (a2.x + a3.x);
        acc.y += (a0.y + a1.y) + (a2.y + a3.y);
        acc.z += (c0.x + c1.x) + (c2.x + c3.x);
        acc.w += (c0.y + c1.y) + (c2.y + c3.y);
    }
    for (; j < je; ++j) {
        h4 vv = table[(unsigned)esrc[j] * 10u + q];
        float2 a = __half22float2(vv.a), c = __half22float2(vv.b);
        acc.x += a.x; acc.y += a.y; acc.z += c.x; acc.w += c.y;
    }
    float dd = dinv[d];
    float4 bb = ((const float4*)b2)[q];
    ((float4*)(out + (size_t)d * DOUT))[q] =
        make_float4(dd * acc.x + bb.x, dd * acc.y + bb.y,
                    dd * acc.z + bb.z, dd * acc.w + bb.w);
}

extern "C" void kernel_launch(void* const* d_in, const int* in_sizes, int n_in,
                              void* d_out, int out_size, void* d_ws, size_t ws_size,
                              hipStream_t stream) {
    const float* x  = (const float*)d_in[0];
    const float* W1 = (const float*)d_in[1];
    const float* b1 = (const float*)d_in[2];
    const float* W2 = (const float*)d_in[3];
    const float* b2 = (const float*)d_in[4];
    const int*   ei = (const int*)d_in[5];
    const int* src = ei;        // edge_index[0]
    const int* dst = ei + EE;   // edge_index[1]
    float* out = (float*)d_out;

    float* ws = (float*)d_ws;
    int*    bucket_cnt    = (int*)ws;                   // [0,256)
    int*    bucket_offs   = (int*)ws + 256;             // [256,512) NB+1 used
    int*    bucket_cursor = (int*)ws + 512;             // [512,768)
    int*    offs          = (int*)ws + 1024;            // NN+1
    float*  dinv          = ws + 101056;                // NN
    int*    esrc          = (int*)ws + 201056;          // EE
    int*    ebuf          = (int*)ws + 1451056;         // EE packed
    __half* xw1h          = (__half*)(ws + 2701056);    // NN*64 halves = 3.2M floats -> [2701056, 5901056)
    float*  agg1          = ws + 5901056;               // NN*64 f32 -> [5901056, 12301056)
    __half* hw2h          = xw1h;                       // alias: xw1h dead after k_agg1; NN*40 halves fits
    // total: 12,301,056 floats = 49.2 MB

    kA_zero    <<<1, 256, 0, stream>>>(bucket_cnt);
    kA_hist    <<<1024, 256, 0, stream>>>(dst, bucket_cnt);
    kA_scanb   <<<1, 256, 0, stream>>>(bucket_cnt, bucket_offs, bucket_cursor);
    kA_scatter <<<(EE + CH - 1) / CH, 256, 0, stream>>>(src, dst, bucket_cursor, ebuf);
    kB_csr     <<<NB, 256, 0, stream>>>(ebuf, bucket_offs, offs, dinv, esrc);
    k_gemm1    <<<(NN + 63) / 64, 256, 0, stream>>>(x, W1, dinv, xw1h);
    k_agg1     <<<(NN + 3) / 4, 256, 0, stream>>>(xw1h, dinv, offs, esrc, agg1);
    k_gemm2    <<<(NN + 63) / 64, 256, 0, stream>>>(agg1, b1, W2, dinv, hw2h);
    k_agg2     <<<(NN + 23) / 24, 256, 0, stream>>>(hw2h, dinv, offs, esrc, b2, out);
}

// Round 8
// 278.366 us; speedup vs baseline: 2.7927x; 1.1142x over previous
//
#include <hip/hip_runtime.h>
#include <hip/hip_fp16.h>

#define NN   100000
#define EE   1250000
#define DIN  128
#define HID  64
#define DOUT 40

#define BN   512                  // nodes per bucket
#define NB   196                  // ceil(NN/BN)
#define CH   4096                 // edges per scatter block (16/thread)

struct __align__(8) h4 { __half2 a, b; };   // 4 halves, one dwordx2 load

// ---------------- CSR construction (bucketed, write-friendly) ----------------

__global__ __launch_bounds__(256) void kA_zero(int* __restrict__ bucket_cnt) {
    int t = threadIdx.x;
    if (t < NB) bucket_cnt[t] = 0;
}

// histogram edges by dst bucket (dst>>9)
__global__ __launch_bounds__(256) void kA_hist(const int* __restrict__ dst,
                                               int* __restrict__ bucket_cnt) {
    __shared__ int h[NB];
    int t = threadIdx.x;
    for (int i = t; i < NB; i += 256) h[i] = 0;
    __syncthreads();
    int stride = gridDim.x * 256;
    for (int e = blockIdx.x * 256 + t; e < EE; e += stride)
        atomicAdd(&h[dst[e] >> 9], 1);
    __syncthreads();
    for (int i = t; i < NB; i += 256)
        if (h[i]) atomicAdd(&bucket_cnt[i], h[i]);
}

// single-block scan of bucket counts -> bucket_offs, init bucket_cursor
__global__ __launch_bounds__(256) void kA_scanb(const int* __restrict__ bucket_cnt,
                                                int* __restrict__ bucket_offs,
                                                int* __restrict__ bucket_cursor) {
    __shared__ int a[256], b[256];
    int t = threadIdx.x;
    int v = (t < NB) ? bucket_cnt[t] : 0;
    a[t] = v;
    __syncthreads();
    int* s = a; int* d = b;
    for (int off = 1; off < 256; off <<= 1) {
        d[t] = s[t] + ((t >= off) ? s[t - off] : 0);
        __syncthreads();
        int* tmp = s; s = d; d = tmp;
    }
    int incl = s[t];
    if (t < NB) {
        bucket_offs[t]   = incl - v;
        bucket_cursor[t] = incl - v;
    }
    if (t == NB - 1) bucket_offs[NB] = incl;   // == EE
}

// block counting-sort: scatter packed (src<<9|local_dst) into bucket segments
__global__ __launch_bounds__(256) void kA_scatter(const int* __restrict__ src,
                                                  const int* __restrict__ dst,
                                                  int* __restrict__ bucket_cursor,
                                                  int* __restrict__ ebuf) {
    __shared__ int hist[NB], gbase[NB], rcur[NB];
    int t = threadIdx.x;
    for (int i = t; i < NB; i += 256) { hist[i] = 0; rcur[i] = 0; }
    __syncthreads();
    int e0 = blockIdx.x * CH;
    int ep[16], eb[16];
    #pragma unroll
    for (int j = 0; j < 16; ++j) {
        int e = e0 + j * 256 + t;
        bool valid = (e < EE);
        if (valid) {
            int dd_ = dst[e];
            ep[j] = (src[e] << 9) | (dd_ & 511);
            eb[j] = dd_ >> 9;
            atomicAdd(&hist[eb[j]], 1);
        } else {
            ep[j] = 0; eb[j] = -1;
        }
    }
    __syncthreads();
    for (int i = t; i < NB; i += 256)
        gbase[i] = atomicAdd(&bucket_cursor[i], hist[i]);
    __syncthreads();
    #pragma unroll
    for (int j = 0; j < 16; ++j) {
        if (eb[j] >= 0) {
            int r = atomicAdd(&rcur[eb[j]], 1);
            ebuf[gbase[eb[j]] + r] = ep[j];
        }
    }
}

// one block per bucket: exact CSR for its 512 nodes, all writes block-local
__global__ __launch_bounds__(256) void kB_csr(const int* __restrict__ ebuf,
                                              const int* __restrict__ bucket_offs,
                                              int* __restrict__ offs,
                                              float* __restrict__ dinv,
                                              int* __restrict__ esrc) {
    __shared__ int lcnt[BN], sA[BN], sB[BN], lcur[BN];
    int t = threadIdx.x;
    int b = blockIdx.x;
    lcnt[t] = 0; lcnt[t + 256] = 0;
    __syncthreads();
    int ebeg = bucket_offs[b], eend = bucket_offs[b + 1];
    for (int j = ebeg + t; j < eend; j += 256)
        atomicAdd(&lcnt[ebuf[j] & 511], 1);
    __syncthreads();
    sA[t] = lcnt[t]; sA[t + 256] = lcnt[t + 256];
    __syncthreads();
    int* s = sA; int* d = sB;
    for (int off = 1; off < BN; off <<= 1) {
        d[t] = s[t] + ((t >= off) ? s[t - off] : 0);
        int i2 = t + 256;
        d[i2] = s[i2] + ((i2 >= off) ? s[i2 - off] : 0);
        __syncthreads();
        int* tmp = s; s = d; d = tmp;
    }
    int base_node = b * BN;
    #pragma unroll
    for (int k = 0; k < 2; ++k) {
        int i = t + k * 256;
        int excl = s[i] - lcnt[i];
        lcur[i] = excl;
        int node = base_node + i;
        if (node < NN) {
            offs[node] = ebeg + excl;
            dinv[node] = rsqrtf((float)lcnt[i] + 1.0f);   // +1 self-loop
        }
    }
    if (b == NB - 1 && t == 0) offs[NN] = EE;
    __syncthreads();
    for (int j = ebeg + t; j < eend; j += 256) {
        int p = ebuf[j];
        int r = atomicAdd(&lcur[p & 511], 1);
        esrc[ebeg + r] = p >> 9;   // scattered only within this block's segment
    }
}

// ---------------- layer 1 GEMM: xw1h = fp16(dinv * (x @ W1)) ----------------
// __launch_bounds__(256,4): cap VGPR<=128 (r7: full unroll bloated to 256 VGPR,
// 8.8% occupancy). #pragma unroll 2 keeps live LDS-load set small.
__global__ __launch_bounds__(256, 4) void k_gemm1(const float* __restrict__ x,
                                                  const float* __restrict__ W1,
                                                  const float* __restrict__ dinv,
                                                  __half* __restrict__ xw1h) {
    __shared__ float sw[DIN * HID];     // [k][c], 32 KB
    __shared__ float sx[64 * 132];      // rows padded to 132 floats (33 float4)
    int t = threadIdx.x;
    const float4* w4g = (const float4*)W1;
    float4* sw4 = (float4*)sw;
    #pragma unroll
    for (int j = 0; j < 8; ++j) sw4[t + j * 256] = w4g[t + j * 256];
    int row0 = blockIdx.x * 64;
    float4* sx4 = (float4*)sx;
    #pragma unroll
    for (int j = 0; j < 8; ++j) {
        int idx = t + j * 256;          // 2048 float4 = 64 rows x 32
        int r = idx >> 5, k4 = idx & 31;
        int row = row0 + r;
        float4 v = (row < NN) ? ((const float4*)(x + (size_t)row * DIN))[k4]
                              : make_float4(0.f, 0.f, 0.f, 0.f);
        sx4[r * 33 + k4] = v;
    }
    __syncthreads();
    int tx = t & 15;        // channel group: c = tx*4 .. +3
    int rg = t >> 4;        // row group: rows rg*4 .. +3
    float4 acc[4];
    #pragma unroll
    for (int r4 = 0; r4 < 4; ++r4) acc[r4] = make_float4(0.f, 0.f, 0.f, 0.f);
    #pragma unroll 2
    for (int k0 = 0; k0 < DIN; k0 += 4) {
        float4 w0 = sw4[(k0 + 0) * 16 + tx];
        float4 w1 = sw4[(k0 + 1) * 16 + tx];
        float4 w2 = sw4[(k0 + 2) * 16 + tx];
        float4 w3 = sw4[(k0 + 3) * 16 + tx];
        #pragma unroll
        for (int r4 = 0; r4 < 4; ++r4) {
            float4 xv = sx4[(rg * 4 + r4) * 33 + (k0 >> 2)];
            acc[r4].x += xv.x * w0.x + xv.y * w1.x + xv.z * w2.x + xv.w * w3.x;
            acc[r4].y += xv.x * w0.y + xv.y * w1.y + xv.z * w2.y + xv.w * w3.y;
            acc[r4].z += xv.x * w0.z + xv.y * w1.z + xv.z * w2.z + xv.w * w3.z;
            acc[r4].w += xv.x * w0.w + xv.y * w1.w + xv.z * w2.w + xv.w * w3.w;
        }
    }
    #pragma unroll
    for (int r4 = 0; r4 < 4; ++r4) {
        int row = row0 + rg * 4 + r4;
        if (row < NN) {
            float di = dinv[row];
            float4 o = acc[r4];
            float2 st;
            ((__half2*)&st)[0] = __floats2half2_rn(o.x * di, o.y * di);
            ((__half2*)&st)[1] = __floats2half2_rn(o.z * di, o.w * di);
            ((float2*)(xw1h + (size_t)row * HID))[tx] = st;
        }
    }
}

// ---------------- layer 1 aggregation: 4 edges/wave, 8B loads ----------------
__global__ __launch_bounds__(256) void k_agg1(const __half* __restrict__ xw1h,
                                              const float* __restrict__ dinv,
                                              const int* __restrict__ offs,
                                              const int* __restrict__ esrc,
                                              float* __restrict__ agg1) {
    int d = blockIdx.x * 4 + (threadIdx.x >> 6);
    if (d >= NN) return;
    int l  = threadIdx.x & 63;
    int eg = l >> 4;                    // edge group 0..3
    int q  = l & 15;                    // h4 index within row (16 h4 = 64 ch)
    const h4* table = (const h4*)xw1h;
    float4 acc = make_float4(0.f, 0.f, 0.f, 0.f);
    if (eg == 0) {                      // self-loop term counted once
        h4 v = table[(unsigned)d * 16u + q];
        float2 f0 = __half22float2(v.a), f1 = __half22float2(v.b);
        acc = make_float4(f0.x, f0.y, f1.x, f1.y);
    }
    int jb = offs[d], je = offs[d + 1];
    int j = jb + eg;
    for (; j + 4 < je; j += 8) {        // 2 rows in flight per group = 8 per wave
        int s0 = esrc[j];
        int s1 = esrc[j + 4];
        h4 v0 = table[(unsigned)s0 * 16u + q];
        h4 v1 = table[(unsigned)s1 * 16u + q];
        float2 a0 = __half22float2(v0.a), b0 = __half22float2(v0.b);
        float2 a1 = __half22float2(v1.a), b1 = __half22float2(v1.b);
        acc.x += a0.x + a1.x; acc.y += a0.y + a1.y;
        acc.z += b0.x + b1.x; acc.w += b0.y + b1.y;
    }
    if (j < je) {
        int s = esrc[j];
        h4 v = table[(unsigned)s * 16u + q];
        float2 a = __half22float2(v.a), b = __half22float2(v.b);
        acc.x += a.x; acc.y += a.y; acc.z += b.x; acc.w += b.y;
    }
    // reduce across the 4 edge groups (lanes q, q+16, q+32, q+48)
    acc.x += __shfl_xor(acc.x, 16); acc.y += __shfl_xor(acc.y, 16);
    acc.z += __shfl_xor(acc.z, 16); acc.w += __shfl_xor(acc.w, 16);
    acc.x += __shfl_xor(acc.x, 32); acc.y += __shfl_xor(acc.y, 32);
    acc.z += __shfl_xor(acc.z, 32); acc.w += __shfl_xor(acc.w, 32);
    if (l < 16) {
        float dd = dinv[d];
        ((float4*)(agg1 + (size_t)d * HID))[q] =
            make_float4(dd * acc.x, dd * acc.y, dd * acc.z, dd * acc.w);
    }
}

// ---------------- layer 2 GEMM: hw2h = fp16(dinv * (relu(agg1+b1) @ W2)) ----------------
// same VGPR-cap treatment as k_gemm1 (was 256 VGPR / 8.8% occupancy in r7)
__global__ __launch_bounds__(256, 4) void k_gemm2(const float* __restrict__ agg1,
                                                  const float* __restrict__ b1,
                                                  const float* __restrict__ W2,
                                                  const float* __restrict__ dinv,
                                                  __half* __restrict__ hw2h) {
    __shared__ float sh[64 * 68];        // rows padded to 68 floats (17 float4)
    __shared__ float sw2l[HID * DOUT];   // [k][j], 10 KB
    int t = threadIdx.x;
    const float4* w4g = (const float4*)W2;
    float4* sw4 = (float4*)sw2l;
    for (int i = t; i < HID * DOUT / 4; i += 256) sw4[i] = w4g[i];
    int row0 = blockIdx.x * 64;
    float4* sh4 = (float4*)sh;
    const float4* b14 = (const float4*)b1;
    #pragma unroll
    for (int j = 0; j < 4; ++j) {
        int idx = t + j * 256;           // 1024 float4 = 64 rows x 16
        int r = idx >> 4, c4 = idx & 15;
        int row = row0 + r;
        float4 v = (row < NN) ? ((const float4*)(agg1 + (size_t)row * HID))[c4]
                              : make_float4(0.f, 0.f, 0.f, 0.f);
        float4 bb = b14[c4];
        v.x = fmaxf(v.x + bb.x, 0.f);
        v.y = fmaxf(v.y + bb.y, 0.f);
        v.z = fmaxf(v.z + bb.z, 0.f);
        v.w = fmaxf(v.w + bb.w, 0.f);
        sh4[r * 17 + c4] = v;
    }
    __syncthreads();
    int tx = t & 15;        // 10 active channel groups
    int rg = t >> 4;
    if (tx < 10) {
        float4 acc[4];
        #pragma unroll
        for (int r4 = 0; r4 < 4; ++r4) acc[r4] = make_float4(0.f, 0.f, 0.f, 0.f);
        #pragma unroll 2
        for (int k0 = 0; k0 < HID; k0 += 4) {
            float4 w0 = sw4[(k0 + 0) * 10 + tx];
            float4 w1 = sw4[(k0 + 1) * 10 + tx];
            float4 w2 = sw4[(k0 + 2) * 10 + tx];
            float4 w3 = sw4[(k0 + 3) * 10 + tx];
            #pragma unroll
            for (int r4 = 0; r4 < 4; ++r4) {
                float4 xv = sh4[(rg * 4 + r4) * 17 + (k0 >> 2)];
                acc[r4].x += xv.x * w0.x + xv.y * w1.x + xv.z * w2.x + xv.w * w3.x;
                acc[r4].y += xv.x * w0.y + xv.y * w1.y + xv.z * w2.y + xv.w * w3.y;
                acc[r4].z += xv.x * w0.z + xv.y * w1.z + xv.z * w2.z + xv.w * w3.z;
                acc[r4].w += xv.x * w0.w + xv.y * w1.w + xv.z * w2.w + xv.w * w3.w;
            }
        }
        #pragma unroll
        for (int r4 = 0; r4 < 4; ++r4) {
            int row = row0 + rg * 4 + r4;
            if (row < NN) {
                float di = dinv[row];
                float4 o = acc[r4];
                float2 st;
                ((__half2*)&st)[0] = __floats2half2_rn(o.x * di, o.y * di);
                ((__half2*)&st)[1] = __floats2half2_rn(o.z * di, o.w * di);
                ((float2*)(hw2h + (size_t)row * DOUT))[tx] = st;
            }
        }
    }
}

// ---------------- layer 2 aggregation: 10 lanes/row, 8B loads ----------------
__global__ __launch_bounds__(256) void k_agg2(const __half* __restrict__ hw2h,
                                              const float* __restrict__ dinv,
                                              const int* __restrict__ offs,
                                              const int* __restrict__ esrc,
                                              const float* __restrict__ b2,
                                              float* __restrict__ out) {
    int t = threadIdx.x;
    if (t >= 240) return;
    int g = t / 10;                     // dst slot 0..23
    int q = t % 10;                     // h4 index within row (10 h4 = 40 ch)
    int d = blockIdx.x * 24 + g;
    if (d >= NN) return;
    const h4* table = (const h4*)hw2h;
    h4 v = table[(unsigned)d * 10u + q];   // self-loop term
    float2 f0 = __half22float2(v.a), f1 = __half22float2(v.b);
    float4 acc = make_float4(f0.x, f0.y, f1.x, f1.y);
    int jb = offs[d], je = offs[d + 1];
    int j = jb;
    for (; j + 3 < je; j += 4) {        // 4 rows in flight per group
        int s0 = esrc[j],     s1 = esrc[j + 1];
        int s2 = esrc[j + 2], s3 = esrc[j + 3];
        h4 v0 = table[(unsigned)s0 * 10u + q];
        h4 v1 = table[(unsigned)s1 * 10u + q];
        h4 v2 = table[(unsigned)s2 * 10u + q];
        h4 v3 = table[(unsigned)s3 * 10u + q];
        float2 a0 = __half22float2(v0.a), c0 = __half22float2(v0.b);
        float2 a1 = __half22float2(v1.a), c1 = __half22float2(v1.b);
        float2 a2 = __half22float2(v2.a), c2 = __half22float2(v2.b);
        float2 a3 = __half22float2(v3.a), c3 = __half22float2(v3.b);
        acc.x += (a0.x + a1.x) + (a2.x + a3.x);
        acc.y += (a0.y + a1.y) + (a2.y + a3.y);
        acc.z += (c0.x + c1.x) + (c2.x + c3.x);
        acc.w += (c0.y + c1.y) + (c2.y + c3.y);
    }
    for (; j < je; ++j) {
        h4 vv = table[(unsigned)esrc[j] * 10u + q];
        float2 a = __half22float2(vv.a), c = __half22float2(vv.b);
        acc.x += a.x; acc.y += a.y; acc.z += c.x; acc.w += c.y;
    }
    float dd = dinv[d];
    float4 bb = ((const float4*)b2)[q];
    ((float4*)(out + (size_t)d * DOUT))[q] =
        make_float4(dd * acc.x + bb.x, dd * acc.y + bb.y,
                    dd * acc.z + bb.z, dd * acc.w + bb.w);
}

extern "C" void kernel_launch(void* const* d_in, const int* in_sizes, int n_in,
                              void* d_out, int out_size, void* d_ws, size_t ws_size,
                              hipStream_t stream) {
    const float* x  = (const float*)d_in[0];
    const float* W1 = (const float*)d_in[1];
    const float* b1 = (const float*)d_in[2];
    const float* W2 = (const float*)d_in[3];
    const float* b2 = (const float*)d_in[4];
    const int*   ei = (const int*)d_in[5];
    const int* src = ei;        // edge_index[0]
    const int* dst = ei + EE;   // edge_index[1]
    float* out = (float*)d_out;

    float* ws = (float*)d_ws;
    int*    bucket_cnt    = (int*)ws;                   // [0,256)
    int*    bucket_offs   = (int*)ws + 256;             // [256,512) NB+1 used
    int*    bucket_cursor = (int*)ws + 512;             // [512,768)
    int*    offs          = (int*)ws + 1024;            // NN+1
    float*  dinv          = ws + 101056;                // NN
    int*    esrc          = (int*)ws + 201056;          // EE
    int*    ebuf          = (int*)ws + 1451056;         // EE packed
    __half* xw1h          = (__half*)(ws + 2701056);    // NN*64 halves = 3.2M floats -> [2701056, 5901056)
    float*  agg1          = ws + 5901056;               // NN*64 f32 -> [5901056, 12301056)
    __half* hw2h          = xw1h;                       // alias: xw1h dead after k_agg1; NN*40 halves fits
    // total: 12,301,056 floats = 49.2 MB

    kA_zero    <<<1, 256, 0, stream>>>(bucket_cnt);
    kA_hist    <<<1024, 256, 0, stream>>>(dst, bucket_cnt);
    kA_scanb   <<<1, 256, 0, stream>>>(bucket_cnt, bucket_offs, bucket_cursor);
    kA_scatter <<<(EE + CH - 1) / CH, 256, 0, stream>>>(src, dst, bucket_cursor, ebuf);
    kB_csr     <<<NB, 256, 0, stream>>>(ebuf, bucket_offs, offs, dinv, esrc);
    k_gemm1    <<<(NN + 63) / 64, 256, 0, stream>>>(x, W1, dinv, xw1h);
    k_agg1     <<<(NN + 3) / 4, 256, 0, stream>>>(xw1h, dinv, offs, esrc, agg1);
    k_gemm2    <<<(NN + 63) / 64, 256, 0, stream>>>(agg1, b1, W2, dinv, hw2h);
    k_agg2     <<<(NN + 23) / 24, 256, 0, stream>>>(hw2h, dinv, offs, esrc, b2, out);
}

// Round 9
// 246.073 us; speedup vs baseline: 3.1592x; 1.1312x over previous
//
#include <hip/hip_runtime.h>
#include <hip/hip_fp16.h>

#define NN   100000
#define EE   1250000
#define DIN  128
#define HID  64
#define DOUT 40

#define BN   512                  // nodes per bucket
#define NB   196                  // ceil(NN/BN)
#define CH   4096                 // edges per scatter block (16/thread)

struct __align__(8) h4 { __half2 a, b; };   // 4 halves, one dwordx2 load

typedef _Float16 v8h __attribute__((ext_vector_type(8)));
typedef float    v4f __attribute__((ext_vector_type(4)));

// ---------------- CSR construction (bucketed, write-friendly) ----------------

__global__ __launch_bounds__(256) void kA_zero(int* __restrict__ bucket_cnt) {
    int t = threadIdx.x;
    if (t < NB) bucket_cnt[t] = 0;
}

__global__ __launch_bounds__(256) void kA_hist(const int* __restrict__ dst,
                                               int* __restrict__ bucket_cnt) {
    __shared__ int h[NB];
    int t = threadIdx.x;
    for (int i = t; i < NB; i += 256) h[i] = 0;
    __syncthreads();
    int stride = gridDim.x * 256;
    for (int e = blockIdx.x * 256 + t; e < EE; e += stride)
        atomicAdd(&h[dst[e] >> 9], 1);
    __syncthreads();
    for (int i = t; i < NB; i += 256)
        if (h[i]) atomicAdd(&bucket_cnt[i], h[i]);
}

__global__ __launch_bounds__(256) void kA_scanb(const int* __restrict__ bucket_cnt,
                                                int* __restrict__ bucket_offs,
                                                int* __restrict__ bucket_cursor) {
    __shared__ int a[256], b[256];
    int t = threadIdx.x;
    int v = (t < NB) ? bucket_cnt[t] : 0;
    a[t] = v;
    __syncthreads();
    int* s = a; int* d = b;
    for (int off = 1; off < 256; off <<= 1) {
        d[t] = s[t] + ((t >= off) ? s[t - off] : 0);
        __syncthreads();
        int* tmp = s; s = d; d = tmp;
    }
    int incl = s[t];
    if (t < NB) {
        bucket_offs[t]   = incl - v;
        bucket_cursor[t] = incl - v;
    }
    if (t == NB - 1) bucket_offs[NB] = incl;   // == EE
}

__global__ __launch_bounds__(256) void kA_scatter(const int* __restrict__ src,
                                                  const int* __restrict__ dst,
                                                  int* __restrict__ bucket_cursor,
                                                  int* __restrict__ ebuf) {
    __shared__ int hist[NB], gbase[NB], rcur[NB];
    int t = threadIdx.x;
    for (int i = t; i < NB; i += 256) { hist[i] = 0; rcur[i] = 0; }
    __syncthreads();
    int e0 = blockIdx.x * CH;
    int ep[16], eb[16];
    #pragma unroll
    for (int j = 0; j < 16; ++j) {
        int e = e0 + j * 256 + t;
        bool valid = (e < EE);
        if (valid) {
            int dd_ = dst[e];
            ep[j] = (src[e] << 9) | (dd_ & 511);
            eb[j] = dd_ >> 9;
            atomicAdd(&hist[eb[j]], 1);
        } else {
            ep[j] = 0; eb[j] = -1;
        }
    }
    __syncthreads();
    for (int i = t; i < NB; i += 256)
        gbase[i] = atomicAdd(&bucket_cursor[i], hist[i]);
    __syncthreads();
    #pragma unroll
    for (int j = 0; j < 16; ++j) {
        if (eb[j] >= 0) {
            int r = atomicAdd(&rcur[eb[j]], 1);
            ebuf[gbase[eb[j]] + r] = ep[j];
        }
    }
}

__global__ __launch_bounds__(256) void kB_csr(const int* __restrict__ ebuf,
                                              const int* __restrict__ bucket_offs,
                                              int* __restrict__ offs,
                                              float* __restrict__ dinv,
                                              int* __restrict__ esrc) {
    __shared__ int lcnt[BN], sA[BN], sB[BN], lcur[BN];
    int t = threadIdx.x;
    int b = blockIdx.x;
    lcnt[t] = 0; lcnt[t + 256] = 0;
    __syncthreads();
    int ebeg = bucket_offs[b], eend = bucket_offs[b + 1];
    for (int j = ebeg + t; j < eend; j += 256)
        atomicAdd(&lcnt[ebuf[j] & 511], 1);
    __syncthreads();
    sA[t] = lcnt[t]; sA[t + 256] = lcnt[t + 256];
    __syncthreads();
    int* s = sA; int* d = sB;
    for (int off = 1; off < BN; off <<= 1) {
        d[t] = s[t] + ((t >= off) ? s[t - off] : 0);
        int i2 = t + 256;
        d[i2] = s[i2] + ((i2 >= off) ? s[i2 - off] : 0);
        __syncthreads();
        int* tmp = s; s = d; d = tmp;
    }
    int base_node = b * BN;
    #pragma unroll
    for (int k = 0; k < 2; ++k) {
        int i = t + k * 256;
        int excl = s[i] - lcnt[i];
        lcur[i] = excl;
        int node = base_node + i;
        if (node < NN) {
            offs[node] = ebeg + excl;
            dinv[node] = rsqrtf((float)lcnt[i] + 1.0f);   // +1 self-loop
        }
    }
    if (b == NB - 1 && t == 0) offs[NN] = EE;
    __syncthreads();
    for (int j = ebeg + t; j < eend; j += 256) {
        int p = ebuf[j];
        int r = atomicAdd(&lcur[p & 511], 1);
        esrc[ebeg + r] = p >> 9;   // scattered only within this block's segment
    }
}

// ---------------- W1 -> B-fragment pre-pack (fp16) ----------------
// frag entry e = (ct*4+ki)*64 + lane; element j = W1[ki*32 + (lane>>4)*8 + j][ct*16 + (lane&15)]
__global__ __launch_bounds__(256) void k_wprep(const float* __restrict__ W1,
                                               __half* __restrict__ w1frag) {
    int e = blockIdx.x * 256 + threadIdx.x;
    if (e >= 1024) return;
    int ct = e >> 8, ki = (e >> 6) & 3, l = e & 63;
    int q = l >> 4, n = l & 15;
    v8h o;
    #pragma unroll
    for (int j = 0; j < 8; ++j)
        o[j] = (_Float16)W1[(ki * 32 + q * 8 + j) * 64 + ct * 16 + n];
    ((v8h*)w1frag)[e] = o;
}

// ---------------- layer 1 GEMM via MFMA: xw1h = fp16(dinv * (x @ W1)) ----------------
// block = 4 waves; wave computes 16 rows x 64 cols. A from global (f32->f16),
// B frags staged in LDS (16 KB, dense per-lane b128 -> conflict-free).
// Layouts (cdna_hip_programming §3, verified m89/m91/m120):
//   A[m=lane&15][k=(lane>>4)*8+j], B[k=(lane>>4)*8+j][n=lane&15],
//   D col=lane&15, row=(lane>>4)*4+reg.
__global__ __launch_bounds__(256) void k_gemm1(const float* __restrict__ x,
                                               const __half* __restrict__ w1frag,
                                               const float* __restrict__ dinv,
                                               __half* __restrict__ xw1h) {
    __shared__ float4 sb4[1024];        // 16 KB: 16 frags x 64 lanes x 16 B
    int t = threadIdx.x;
    const float4* wf = (const float4*)w1frag;
    #pragma unroll
    for (int i = 0; i < 4; ++i) sb4[t + i * 256] = wf[t + i * 256];
    __syncthreads();
    const v8h* sbh = (const v8h*)sb4;

    int wv = t >> 6, l = t & 63;
    int q = l >> 4, n = l & 15;
    int row0 = blockIdx.x * 64 + wv * 16;
    int m = row0 + n;                   // A-operand row for this lane
    bool mv = (m < NN);
    const float* xr = x + (size_t)(mv ? m : 0) * DIN + q * 8;
    v8h afrag[4];
    #pragma unroll
    for (int ki = 0; ki < 4; ++ki) {
        float4 u0 = mv ? ((const float4*)(xr + ki * 32))[0] : make_float4(0.f,0.f,0.f,0.f);
        float4 u1 = mv ? ((const float4*)(xr + ki * 32))[1] : make_float4(0.f,0.f,0.f,0.f);
        v8h a;
        a[0] = (_Float16)u0.x; a[1] = (_Float16)u0.y;
        a[2] = (_Float16)u0.z; a[3] = (_Float16)u0.w;
        a[4] = (_Float16)u1.x; a[5] = (_Float16)u1.y;
        a[6] = (_Float16)u1.z; a[7] = (_Float16)u1.w;
        afrag[ki] = a;
    }
    v4f acc[4];
    #pragma unroll
    for (int ct = 0; ct < 4; ++ct) acc[ct] = (v4f){0.f, 0.f, 0.f, 0.f};
    #pragma unroll
    for (int ct = 0; ct < 4; ++ct) {
        #pragma unroll
        for (int ki = 0; ki < 4; ++ki)
            acc[ct] = __builtin_amdgcn_mfma_f32_16x16x32_f16(
                afrag[ki], sbh[(ct * 4 + ki) * 64 + l], acc[ct], 0, 0, 0);
    }
    // D: row = row0 + q*4 + r, col = ct*16 + n
    _Float16* outh = (_Float16*)xw1h;
    #pragma unroll
    for (int r = 0; r < 4; ++r) {
        int rr = row0 + q * 4 + r;
        if (rr < NN) {
            float di = dinv[rr];
            #pragma unroll
            for (int ct = 0; ct < 4; ++ct)
                outh[(size_t)rr * HID + ct * 16 + n] = (_Float16)(acc[ct][r] * di);
        }
    }
}

// ---------------- layer 1 aggregation: one 16-lane group per dst ----------------
// 16 dsts/block; group walks its dst's full edge list, unroll-4 -> 16 rows
// in flight per wave; no cross-group reduce.
__global__ __launch_bounds__(256) void k_agg1(const __half* __restrict__ xw1h,
                                              const float* __restrict__ dinv,
                                              const int* __restrict__ offs,
                                              const int* __restrict__ esrc,
                                              float* __restrict__ agg1) {
    int t = threadIdx.x;
    int g = t >> 4;                     // dst slot 0..15
    int q = t & 15;                     // h4 index within row (16 h4 = 64 ch)
    int d = blockIdx.x * 16 + g;
    if (d >= NN) return;
    const h4* table = (const h4*)xw1h;
    h4 v = table[(unsigned)d * 16u + q];   // self-loop term
    float2 f0 = __half22float2(v.a), f1 = __half22float2(v.b);
    float4 acc = make_float4(f0.x, f0.y, f1.x, f1.y);
    int j = offs[d], je = offs[d + 1];
    for (; j + 3 < je; j += 4) {
        int s0 = esrc[j],     s1 = esrc[j + 1];
        int s2 = esrc[j + 2], s3 = esrc[j + 3];
        h4 v0 = table[(unsigned)s0 * 16u + q];
        h4 v1 = table[(unsigned)s1 * 16u + q];
        h4 v2 = table[(unsigned)s2 * 16u + q];
        h4 v3 = table[(unsigned)s3 * 16u + q];
        float2 a0 = __half22float2(v0.a), c0 = __half22float2(v0.b);
        float2 a1 = __half22float2(v1.a), c1 = __half22float2(v1.b);
        float2 a2 = __half22float2(v2.a), c2 = __half22float2(v2.b);
        float2 a3 = __half22float2(v3.a), c3 = __half22float2(v3.b);
        acc.x += (a0.x + a1.x) + (a2.x + a3.x);
        acc.y += (a0.y + a1.y) + (a2.y + a3.y);
        acc.z += (c0.x + c1.x) + (c2.x + c3.x);
        acc.w += (c0.y + c1.y) + (c2.y + c3.y);
    }
    for (; j < je; ++j) {
        h4 vv = table[(unsigned)esrc[j] * 16u + q];
        float2 a = __half22float2(vv.a), c = __half22float2(vv.b);
        acc.x += a.x; acc.y += a.y; acc.z += c.x; acc.w += c.y;
    }
    float dd = dinv[d];
    ((float4*)(agg1 + (size_t)d * HID))[q] =
        make_float4(dd * acc.x, dd * acc.y, dd * acc.z, dd * acc.w);
}

// ---------------- layer 2 GEMM: hw2h = fp16(dinv * (relu(agg1+b1) @ W2)) ----------------
__global__ __launch_bounds__(256, 4) void k_gemm2(const float* __restrict__ agg1,
                                                  const float* __restrict__ b1,
                                                  const float* __restrict__ W2,
                                                  const float* __restrict__ dinv,
                                                  __half* __restrict__ hw2h) {
    __shared__ float sh[64 * 68];        // rows padded to 68 floats (17 float4)
    __shared__ float sw2l[HID * DOUT];   // [k][j], 10 KB
    int t = threadIdx.x;
    const float4* w4g = (const float4*)W2;
    float4* sw4 = (float4*)sw2l;
    for (int i = t; i < HID * DOUT / 4; i += 256) sw4[i] = w4g[i];
    int row0 = blockIdx.x * 64;
    float4* sh4 = (float4*)sh;
    const float4* b14 = (const float4*)b1;
    #pragma unroll
    for (int j = 0; j < 4; ++j) {
        int idx = t + j * 256;           // 1024 float4 = 64 rows x 16
        int r = idx >> 4, c4 = idx & 15;
        int row = row0 + r;
        float4 v = (row < NN) ? ((const float4*)(agg1 + (size_t)row * HID))[c4]
                              : make_float4(0.f, 0.f, 0.f, 0.f);
        float4 bb = b14[c4];
        v.x = fmaxf(v.x + bb.x, 0.f);
        v.y = fmaxf(v.y + bb.y, 0.f);
        v.z = fmaxf(v.z + bb.z, 0.f);
        v.w = fmaxf(v.w + bb.w, 0.f);
        sh4[r * 17 + c4] = v;
    }
    __syncthreads();
    int tx = t & 15;        // 10 active channel groups
    int rg = t >> 4;
    if (tx < 10) {
        float4 acc[4];
        #pragma unroll
        for (int r4 = 0; r4 < 4; ++r4) acc[r4] = make_float4(0.f, 0.f, 0.f, 0.f);
        #pragma unroll 2
        for (int k0 = 0; k0 < HID; k0 += 4) {
            float4 w0 = sw4[(k0 + 0) * 10 + tx];
            float4 w1 = sw4[(k0 + 1) * 10 + tx];
            float4 w2 = sw4[(k0 + 2) * 10 + tx];
            float4 w3 = sw4[(k0 + 3) * 10 + tx];
            #pragma unroll
            for (int r4 = 0; r4 < 4; ++r4) {
                float4 xv = sh4[(rg * 4 + r4) * 17 + (k0 >> 2)];
                acc[r4].x += xv.x * w0.x + xv.y * w1.x + xv.z * w2.x + xv.w * w3.x;
                acc[r4].y += xv.x * w0.y + xv.y * w1.y + xv.z * w2.y + xv.w * w3.y;
                acc[r4].z += xv.x * w0.z + xv.y * w1.z + xv.z * w2.z + xv.w * w3.z;
                acc[r4].w += xv.x * w0.w + xv.y * w1.w + xv.z * w2.w + xv.w * w3.w;
            }
        }
        #pragma unroll
        for (int r4 = 0; r4 < 4; ++r4) {
            int row = row0 + rg * 4 + r4;
            if (row < NN) {
                float di = dinv[row];
                float4 o = acc[r4];
                float2 st;
                ((__half2*)&st)[0] = __floats2half2_rn(o.x * di, o.y * di);
                ((__half2*)&st)[1] = __floats2half2_rn(o.z * di, o.w * di);
                ((float2*)(hw2h + (size_t)row * DOUT))[tx] = st;
            }
        }
    }
}

// ---------------- layer 2 aggregation: 10 lanes/row, 8B loads ----------------
__global__ __launch_bounds__(256) void k_agg2(const __half* __restrict__ hw2h,
                                              const float* __restrict__ dinv,
                                              const int* __restrict__ offs,
                                              const int* __restrict__ esrc,
                                              const float* __restrict__ b2,
                                              float* __restrict__ out) {
    int t = threadIdx.x;
    if (t >= 240) return;
    int g = t / 10;                     // dst slot 0..23
    int q = t % 10;                     // h4 index within row (10 h4 = 40 ch)
    int d = blockIdx.x * 24 + g;
    if (d >= NN) return;
    const h4* table = (const h4*)hw2h;
    h4 v = table[(unsigned)d * 10u + q];   // self-loop term
    float2 f0 = __half22float2(v.a), f1 = __half22float2(v.b);
    float4 acc = make_float4(f0.x, f0.y, f1.x, f1.y);
    int jb = offs[d], je = offs[d + 1];
    int j = jb;
    for (; j + 3 < je; j += 4) {        // 4 rows in flight per group
        int s0 = esrc[j],     s1 = esrc[j + 1];
        int s2 = esrc[j + 2], s3 = esrc[j + 3];
        h4 v0 = table[(unsigned)s0 * 10u + q];
        h4 v1 = table[(unsigned)s1 * 10u + q];
        h4 v2 = table[(unsigned)s2 * 10u + q];
        h4 v3 = table[(unsigned)s3 * 10u + q];
        float2 a0 = __half22float2(v0.a), c0 = __half22float2(v0.b);
        float2 a1 = __half22float2(v1.a), c1 = __half22float2(v1.b);
        float2 a2 = __half22float2(v2.a), c2 = __half22float2(v2.b);
        float2 a3 = __half22float2(v3.a), c3 = __half22float2(v3.b);
        acc.x += (a0.x + a1.x) + (a2.x + a3.x);
        acc.y += (a0.y + a1.y) + (a2.y + a3.y);
        acc.z += (c0.x + c1.x) + (c2.x + c3.x);
        acc.w += (c0.y + c1.y) + (c2.y + c3.y);
    }
    for (; j < je; ++j) {
        h4 vv = table[(unsigned)esrc[j] * 10u + q];
        float2 a = __half22float2(vv.a), c = __half22float2(vv.b);
        acc.x += a.x; acc.y += a.y; acc.z += c.x; acc.w += c.y;
    }
    float dd = dinv[d];
    float4 bb = ((const float4*)b2)[q];
    ((float4*)(out + (size_t)d * DOUT))[q] =
        make_float4(dd * acc.x + bb.x, dd * acc.y + bb.y,
                    dd * acc.z + bb.z, dd * acc.w + bb.w);
}

extern "C" void kernel_launch(void* const* d_in, const int* in_sizes, int n_in,
                              void* d_out, int out_size, void* d_ws, size_t ws_size,
                              hipStream_t stream) {
    const float* x  = (const float*)d_in[0];
    const float* W1 = (const float*)d_in[1];
    const float* b1 = (const float*)d_in[2];
    const float* W2 = (const float*)d_in[3];
    const float* b2 = (const float*)d_in[4];
    const int*   ei = (const int*)d_in[5];
    const int* src = ei;        // edge_index[0]
    const int* dst = ei + EE;   // edge_index[1]
    float* out = (float*)d_out;

    float* ws = (float*)d_ws;
    int*    bucket_cnt    = (int*)ws;                   // [0,256)
    int*    bucket_offs   = (int*)ws + 256;             // [256,512) NB+1 used
    int*    bucket_cursor = (int*)ws + 512;             // [512,768)
    int*    offs          = (int*)ws + 1024;            // NN+1
    float*  dinv          = ws + 101056;                // NN
    int*    esrc          = (int*)ws + 201056;          // EE
    int*    ebuf          = (int*)ws + 1451056;         // EE packed
    __half* xw1h          = (__half*)(ws + 2701056);    // NN*64 halves = 3.2M floats -> [2701056, 5901056)
    float*  agg1          = ws + 5901056;               // NN*64 f32 -> [5901056, 12301056)
    __half* w1frag        = (__half*)(ws + 12301056);   // 8192 halves -> [12301056, 12305152)
    __half* hw2h          = xw1h;                       // alias: xw1h dead after k_agg1; NN*40 halves fits
    // total: 12,305,152 floats = 49.2 MB

    k_wprep    <<<4, 256, 0, stream>>>(W1, w1frag);
    kA_zero    <<<1, 256, 0, stream>>>(bucket_cnt);
    kA_hist    <<<1024, 256, 0, stream>>>(dst, bucket_cnt);
    kA_scanb   <<<1, 256, 0, stream>>>(bucket_cnt, bucket_offs, bucket_cursor);
    kA_scatter <<<(EE + CH - 1) / CH, 256, 0, stream>>>(src, dst, bucket_cursor, ebuf);
    kB_csr     <<<NB, 256, 0, stream>>>(ebuf, bucket_offs, offs, dinv, esrc);
    k_gemm1    <<<(NN + 63) / 64, 256, 0, stream>>>(x, w1frag, dinv, xw1h);
    k_agg1     <<<(NN + 15) / 16, 256, 0, stream>>>(xw1h, dinv, offs, esrc, agg1);
    k_gemm2    <<<(NN + 63) / 64, 256, 0, stream>>>(agg1, b1, W2, dinv, hw2h);
    k_agg2     <<<(NN + 23) / 24, 256, 0, stream>>>(hw2h, dinv, offs, esrc, b2, out);
}

// Round 10
// 234.165 us; speedup vs baseline: 3.3198x; 1.0509x over previous
//
#include <hip/hip_runtime.h>
#include <hip/hip_fp16.h>

#define NN   100000
#define EE   1250000
#define DIN  128
#define HID  64
#define DOUT 40

#define BN   512                  // nodes per bucket
#define NB   196                  // ceil(NN/BN)
#define CH   4096                 // edges per scatter block (16/thread)

struct __align__(8) h4 { __half2 a, b; };   // 4 halves, one dwordx2 load

typedef _Float16 v8h __attribute__((ext_vector_type(8)));
typedef float    v4f __attribute__((ext_vector_type(4)));

// ---------------- CSR construction (bucketed, write-friendly) ----------------

__global__ __launch_bounds__(256) void kA_zero(int* __restrict__ bucket_cnt) {
    int t = threadIdx.x;
    if (t < NB) bucket_cnt[t] = 0;
}

__global__ __launch_bounds__(256) void kA_hist(const int* __restrict__ dst,
                                               int* __restrict__ bucket_cnt) {
    __shared__ int h[NB];
    int t = threadIdx.x;
    for (int i = t; i < NB; i += 256) h[i] = 0;
    __syncthreads();
    int stride = gridDim.x * 256;
    for (int e = blockIdx.x * 256 + t; e < EE; e += stride)
        atomicAdd(&h[dst[e] >> 9], 1);
    __syncthreads();
    for (int i = t; i < NB; i += 256)
        if (h[i]) atomicAdd(&bucket_cnt[i], h[i]);
}

__global__ __launch_bounds__(256) void kA_scanb(const int* __restrict__ bucket_cnt,
                                                int* __restrict__ bucket_offs,
                                                int* __restrict__ bucket_cursor) {
    __shared__ int a[256], b[256];
    int t = threadIdx.x;
    int v = (t < NB) ? bucket_cnt[t] : 0;
    a[t] = v;
    __syncthreads();
    int* s = a; int* d = b;
    for (int off = 1; off < 256; off <<= 1) {
        d[t] = s[t] + ((t >= off) ? s[t - off] : 0);
        __syncthreads();
        int* tmp = s; s = d; d = tmp;
    }
    int incl = s[t];
    if (t < NB) {
        bucket_offs[t]   = incl - v;
        bucket_cursor[t] = incl - v;
    }
    if (t == NB - 1) bucket_offs[NB] = incl;   // == EE
}

__global__ __launch_bounds__(256) void kA_scatter(const int* __restrict__ src,
                                                  const int* __restrict__ dst,
                                                  int* __restrict__ bucket_cursor,
                                                  int* __restrict__ ebuf) {
    __shared__ int hist[NB], gbase[NB], rcur[NB];
    int t = threadIdx.x;
    for (int i = t; i < NB; i += 256) { hist[i] = 0; rcur[i] = 0; }
    __syncthreads();
    int e0 = blockIdx.x * CH;
    int ep[16], eb[16];
    #pragma unroll
    for (int j = 0; j < 16; ++j) {
        int e = e0 + j * 256 + t;
        bool valid = (e < EE);
        if (valid) {
            int dd_ = dst[e];
            ep[j] = (src[e] << 9) | (dd_ & 511);
            eb[j] = dd_ >> 9;
            atomicAdd(&hist[eb[j]], 1);
        } else {
            ep[j] = 0; eb[j] = -1;
        }
    }
    __syncthreads();
    for (int i = t; i < NB; i += 256)
        gbase[i] = atomicAdd(&bucket_cursor[i], hist[i]);
    __syncthreads();
    #pragma unroll
    for (int j = 0; j < 16; ++j) {
        if (eb[j] >= 0) {
            int r = atomicAdd(&rcur[eb[j]], 1);
            ebuf[gbase[eb[j]] + r] = ep[j];
        }
    }
}

__global__ __launch_bounds__(256) void kB_csr(const int* __restrict__ ebuf,
                                              const int* __restrict__ bucket_offs,
                                              int* __restrict__ offs,
                                              float* __restrict__ dinv,
                                              int* __restrict__ esrc) {
    __shared__ int lcnt[BN], sA[BN], sB[BN], lcur[BN];
    int t = threadIdx.x;
    int b = blockIdx.x;
    lcnt[t] = 0; lcnt[t + 256] = 0;
    __syncthreads();
    int ebeg = bucket_offs[b], eend = bucket_offs[b + 1];
    for (int j = ebeg + t; j < eend; j += 256)
        atomicAdd(&lcnt[ebuf[j] & 511], 1);
    __syncthreads();
    sA[t] = lcnt[t]; sA[t + 256] = lcnt[t + 256];
    __syncthreads();
    int* s = sA; int* d = sB;
    for (int off = 1; off < BN; off <<= 1) {
        d[t] = s[t] + ((t >= off) ? s[t - off] : 0);
        int i2 = t + 256;
        d[i2] = s[i2] + ((i2 >= off) ? s[i2 - off] : 0);
        __syncthreads();
        int* tmp = s; s = d; d = tmp;
    }
    int base_node = b * BN;
    #pragma unroll
    for (int k = 0; k < 2; ++k) {
        int i = t + k * 256;
        int excl = s[i] - lcnt[i];
        lcur[i] = excl;
        int node = base_node + i;
        if (node < NN) {
            offs[node] = ebeg + excl;
            dinv[node] = rsqrtf((float)lcnt[i] + 1.0f);   // +1 self-loop
        }
    }
    if (b == NB - 1 && t == 0) offs[NN] = EE;
    __syncthreads();
    for (int j = ebeg + t; j < eend; j += 256) {
        int p = ebuf[j];
        int r = atomicAdd(&lcur[p & 511], 1);
        esrc[ebeg + r] = p >> 9;   // scattered only within this block's segment
    }
}

// ---------------- W1 & W2 -> B-fragment pre-pack (fp16, one launch) ----------------
// W1: frag e=(ct*4+ki)*64+l, elem j = W1[ki*32+(l>>4)*8+j][ct*16+(l&15)], e<1024
// W2: frag e2=(ct*2+ki)*64+l, elem j = W2[ki*32+(l>>4)*8+j][ct*16+(l&15)] (0 if col>=40), e2<384
__global__ __launch_bounds__(256) void k_wprep(const float* __restrict__ W1,
                                               const float* __restrict__ W2,
                                               __half* __restrict__ w1frag,
                                               __half* __restrict__ w2frag) {
    int e = blockIdx.x * 256 + threadIdx.x;
    if (e < 1024) {
        int ct = e >> 8, ki = (e >> 6) & 3, l = e & 63;
        int q = l >> 4, n = l & 15;
        v8h o;
        #pragma unroll
        for (int j = 0; j < 8; ++j)
            o[j] = (_Float16)W1[(ki * 32 + q * 8 + j) * 64 + ct * 16 + n];
        ((v8h*)w1frag)[e] = o;
    } else {
        int e2 = e - 1024;
        if (e2 < 384) {
            int ct = e2 >> 7, ki = (e2 >> 6) & 1, l = e2 & 63;
            int q = l >> 4, n = l & 15;
            int col = ct * 16 + n;
            v8h o;
            #pragma unroll
            for (int j = 0; j < 8; ++j)
                o[j] = (col < DOUT) ? (_Float16)W2[(ki * 32 + q * 8 + j) * DOUT + col]
                                    : (_Float16)0.0f;
            ((v8h*)w2frag)[e2] = o;
        }
    }
}

// ---------------- layer 1 GEMM via MFMA: xw1h = fp16(dinv * (x @ W1)) ----------------
__global__ __launch_bounds__(256) void k_gemm1(const float* __restrict__ x,
                                               const __half* __restrict__ w1frag,
                                               const float* __restrict__ dinv,
                                               __half* __restrict__ xw1h) {
    __shared__ float4 sb4[1024];        // 16 KB: 16 frags x 64 lanes x 16 B
    int t = threadIdx.x;
    const float4* wf = (const float4*)w1frag;
    #pragma unroll
    for (int i = 0; i < 4; ++i) sb4[t + i * 256] = wf[t + i * 256];
    __syncthreads();
    const v8h* sbh = (const v8h*)sb4;

    int wv = t >> 6, l = t & 63;
    int q = l >> 4, n = l & 15;
    int row0 = blockIdx.x * 64 + wv * 16;
    int m = row0 + n;                   // A-operand row for this lane
    bool mv = (m < NN);
    const float* xr = x + (size_t)(mv ? m : 0) * DIN + q * 8;
    v8h afrag[4];
    #pragma unroll
    for (int ki = 0; ki < 4; ++ki) {
        float4 u0 = mv ? ((const float4*)(xr + ki * 32))[0] : make_float4(0.f,0.f,0.f,0.f);
        float4 u1 = mv ? ((const float4*)(xr + ki * 32))[1] : make_float4(0.f,0.f,0.f,0.f);
        v8h a;
        a[0] = (_Float16)u0.x; a[1] = (_Float16)u0.y;
        a[2] = (_Float16)u0.z; a[3] = (_Float16)u0.w;
        a[4] = (_Float16)u1.x; a[5] = (_Float16)u1.y;
        a[6] = (_Float16)u1.z; a[7] = (_Float16)u1.w;
        afrag[ki] = a;
    }
    v4f acc[4];
    #pragma unroll
    for (int ct = 0; ct < 4; ++ct) acc[ct] = (v4f){0.f, 0.f, 0.f, 0.f};
    #pragma unroll
    for (int ct = 0; ct < 4; ++ct) {
        #pragma unroll
        for (int ki = 0; ki < 4; ++ki)
            acc[ct] = __builtin_amdgcn_mfma_f32_16x16x32_f16(
                afrag[ki], sbh[(ct * 4 + ki) * 64 + l], acc[ct], 0, 0, 0);
    }
    _Float16* outh = (_Float16*)xw1h;
    #pragma unroll
    for (int r = 0; r < 4; ++r) {
        int rr = row0 + q * 4 + r;
        if (rr < NN) {
            float di = dinv[rr];
            #pragma unroll
            for (int ct = 0; ct < 4; ++ct)
                outh[(size_t)rr * HID + ct * 16 + n] = (_Float16)(acc[ct][r] * di);
        }
    }
}

// ---------------- layer 1 aggregation: one 16-lane group per dst, fp16 out ----------------
__global__ __launch_bounds__(256) void k_agg1(const __half* __restrict__ xw1h,
                                              const float* __restrict__ dinv,
                                              const int* __restrict__ offs,
                                              const int* __restrict__ esrc,
                                              __half* __restrict__ agg1h) {
    int t = threadIdx.x;
    int g = t >> 4;                     // dst slot 0..15
    int q = t & 15;                     // h4 index within row (16 h4 = 64 ch)
    int d = blockIdx.x * 16 + g;
    if (d >= NN) return;
    const h4* table = (const h4*)xw1h;
    h4 v = table[(unsigned)d * 16u + q];   // self-loop term
    float2 f0 = __half22float2(v.a), f1 = __half22float2(v.b);
    float4 acc = make_float4(f0.x, f0.y, f1.x, f1.y);
    int j = offs[d], je = offs[d + 1];
    for (; j + 7 < je; j += 8) {
        int ss[8];
        #pragma unroll
        for (int u = 0; u < 8; ++u) ss[u] = esrc[j + u];
        h4 vv[8];
        #pragma unroll
        for (int u = 0; u < 8; ++u) vv[u] = table[(unsigned)ss[u] * 16u + q];
        #pragma unroll
        for (int u = 0; u < 8; ++u) {
            float2 a = __half22float2(vv[u].a), c = __half22float2(vv[u].b);
            acc.x += a.x; acc.y += a.y; acc.z += c.x; acc.w += c.y;
        }
    }
    for (; j + 3 < je; j += 4) {
        int s0 = esrc[j],     s1 = esrc[j + 1];
        int s2 = esrc[j + 2], s3 = esrc[j + 3];
        h4 v0 = table[(unsigned)s0 * 16u + q];
        h4 v1 = table[(unsigned)s1 * 16u + q];
        h4 v2 = table[(unsigned)s2 * 16u + q];
        h4 v3 = table[(unsigned)s3 * 16u + q];
        float2 a0 = __half22float2(v0.a), c0 = __half22float2(v0.b);
        float2 a1 = __half22float2(v1.a), c1 = __half22float2(v1.b);
        float2 a2 = __half22float2(v2.a), c2 = __half22float2(v2.b);
        float2 a3 = __half22float2(v3.a), c3 = __half22float2(v3.b);
        acc.x += (a0.x + a1.x) + (a2.x + a3.x);
        acc.y += (a0.y + a1.y) + (a2.y + a3.y);
        acc.z += (c0.x + c1.x) + (c2.x + c3.x);
        acc.w += (c0.y + c1.y) + (c2.y + c3.y);
    }
    for (; j < je; ++j) {
        h4 vv = table[(unsigned)esrc[j] * 16u + q];
        float2 a = __half22float2(vv.a), c = __half22float2(vv.b);
        acc.x += a.x; acc.y += a.y; acc.z += c.x; acc.w += c.y;
    }
    float dd = dinv[d];
    h4 o;
    o.a = __floats2half2_rn(dd * acc.x, dd * acc.y);
    o.b = __floats2half2_rn(dd * acc.z, dd * acc.w);
    ((h4*)(agg1h + (size_t)d * HID))[q] = o;
}

// ---------------- layer 2 GEMM via MFMA: hw2h = fp16(dinv*(relu(agg1h+b1)@W2)) ----------------
// block = 4 waves x 16 rows. A: direct v8h loads from agg1h + fused bias/relu.
// B: 6 prepacked frags (3 col-tiles x 2 k-frags) in LDS. 6 MFMAs/wave.
__global__ __launch_bounds__(256) void k_gemm2(const __half* __restrict__ agg1h,
                                               const float* __restrict__ b1,
                                               const __half* __restrict__ w2frag,
                                               const float* __restrict__ dinv,
                                               __half* __restrict__ hw2h) {
    __shared__ float4 sb4[384];          // 6 KB: 6 frags x 64 lanes x 16 B
    __shared__ float sb1[64];
    int t = threadIdx.x;
    const float4* wf = (const float4*)w2frag;
    if (t < 192) { sb4[t] = wf[t]; sb4[t + 192] = wf[t + 192]; }
    if (t < 64) sb1[t] = b1[t];
    __syncthreads();
    const v8h* sbh = (const v8h*)sb4;

    int wv = t >> 6, l = t & 63;
    int q = l >> 4, n = l & 15;
    int row0 = blockIdx.x * 64 + wv * 16;
    int m = row0 + n;
    bool mv = (m < NN);
    const v8h* arow = (const v8h*)(agg1h + (size_t)(mv ? m : 0) * HID);
    v8h afrag[2];
    #pragma unroll
    for (int ki = 0; ki < 2; ++ki) {
        v8h a = arow[ki * 4 + q];        // halves [ki*32+q*8 .. +7]
        #pragma unroll
        for (int j = 0; j < 8; ++j) {
            float av = (float)a[j] + sb1[ki * 32 + q * 8 + j];
            a[j] = (_Float16)fmaxf(av, 0.f);
        }
        afrag[ki] = mv ? a : (v8h)(_Float16)0.0f;
    }
    v4f acc[3];
    #pragma unroll
    for (int ct = 0; ct < 3; ++ct) acc[ct] = (v4f){0.f, 0.f, 0.f, 0.f};
    #pragma unroll
    for (int ct = 0; ct < 3; ++ct) {
        #pragma unroll
        for (int ki = 0; ki < 2; ++ki)
            acc[ct] = __builtin_amdgcn_mfma_f32_16x16x32_f16(
                afrag[ki], sbh[(ct * 2 + ki) * 64 + l], acc[ct], 0, 0, 0);
    }
    _Float16* outh = (_Float16*)hw2h;
    #pragma unroll
    for (int r = 0; r < 4; ++r) {
        int rr = row0 + q * 4 + r;
        if (rr < NN) {
            float di = dinv[rr];
            #pragma unroll
            for (int ct = 0; ct < 3; ++ct) {
                int col = ct * 16 + n;
                if (col < DOUT)
                    outh[(size_t)rr * DOUT + col] = (_Float16)(acc[ct][r] * di);
            }
        }
    }
}

// ---------------- layer 2 aggregation: 10 lanes/row, 8B loads ----------------
__global__ __launch_bounds__(256) void k_agg2(const __half* __restrict__ hw2h,
                                              const float* __restrict__ dinv,
                                              const int* __restrict__ offs,
                                              const int* __restrict__ esrc,
                                              const float* __restrict__ b2,
                                              float* __restrict__ out) {
    int t = threadIdx.x;
    if (t >= 240) return;
    int g = t / 10;                     // dst slot 0..23
    int q = t % 10;                     // h4 index within row (10 h4 = 40 ch)
    int d = blockIdx.x * 24 + g;
    if (d >= NN) return;
    const h4* table = (const h4*)hw2h;
    h4 v = table[(unsigned)d * 10u + q];   // self-loop term
    float2 f0 = __half22float2(v.a), f1 = __half22float2(v.b);
    float4 acc = make_float4(f0.x, f0.y, f1.x, f1.y);
    int j = offs[d], je = offs[d + 1];
    for (; j + 7 < je; j += 8) {
        int ss[8];
        #pragma unroll
        for (int u = 0; u < 8; ++u) ss[u] = esrc[j + u];
        h4 vv[8];
        #pragma unroll
        for (int u = 0; u < 8; ++u) vv[u] = table[(unsigned)ss[u] * 10u + q];
        #pragma unroll
        for (int u = 0; u < 8; ++u) {
            float2 a = __half22float2(vv[u].a), c = __half22float2(vv[u].b);
            acc.x += a.x; acc.y += a.y; acc.z += c.x; acc.w += c.y;
        }
    }
    for (; j + 3 < je; j += 4) {
        int s0 = esrc[j],     s1 = esrc[j + 1];
        int s2 = esrc[j + 2], s3 = esrc[j + 3];
        h4 v0 = table[(unsigned)s0 * 10u + q];
        h4 v1 = table[(unsigned)s1 * 10u + q];
        h4 v2 = table[(unsigned)s2 * 10u + q];
        h4 v3 = table[(unsigned)s3 * 10u + q];
        float2 a0 = __half22float2(v0.a), c0 = __half22float2(v0.b);
        float2 a1 = __half22float2(v1.a), c1 = __half22float2(v1.b);
        float2 a2 = __half22float2(v2.a), c2 = __half22float2(v2.b);
        float2 a3 = __half22float2(v3.a), c3 = __half22float2(v3.b);
        acc.x += (a0.x + a1.x) + (a2.x + a3.x);
        acc.y += (a0.y + a1.y) + (a2.y + a3.y);
        acc.z += (c0.x + c1.x) + (c2.x + c3.x);
        acc.w += (c0.y + c1.y) + (c2.y + c3.y);
    }
    for (; j < je; ++j) {
        h4 vv = table[(unsigned)esrc[j] * 10u + q];
        float2 a = __half22float2(vv.a), c = __half22float2(vv.b);
        acc.x += a.x; acc.y += a.y; acc.z += c.x; acc.w += c.y;
    }
    float dd = dinv[d];
    float4 bb = ((const float4*)b2)[q];
    ((float4*)(out + (size_t)d * DOUT))[q] =
        make_float4(dd * acc.x + bb.x, dd * acc.y + bb.y,
                    dd * acc.z + bb.z, dd * acc.w + bb.w);
}

extern "C" void kernel_launch(void* const* d_in, const int* in_sizes, int n_in,
                              void* d_out, int out_size, void* d_ws, size_t ws_size,
                              hipStream_t stream) {
    const float* x  = (const float*)d_in[0];
    const float* W1 = (const float*)d_in[1];
    const float* b1 = (const float*)d_in[2];
    const float* W2 = (const float*)d_in[3];
    const float* b2 = (const float*)d_in[4];
    const int*   ei = (const int*)d_in[5];
    const int* src = ei;        // edge_index[0]
    const int* dst = ei + EE;   // edge_index[1]
    float* out = (float*)d_out;

    float* ws = (float*)d_ws;
    int*    bucket_cnt    = (int*)ws;                   // [0,256)
    int*    bucket_offs   = (int*)ws + 256;             // [256,512) NB+1 used
    int*    bucket_cursor = (int*)ws + 512;             // [512,768)
    int*    offs          = (int*)ws + 1024;            // NN+1
    float*  dinv          = ws + 101056;                // NN
    int*    esrc          = (int*)ws + 201056;          // EE
    int*    ebuf          = (int*)ws + 1451056;         // EE packed
    __half* xw1h          = (__half*)(ws + 2701056);    // NN*64 halves = 3.2M floats -> [2701056, 5901056)
    __half* agg1h         = (__half*)(ws + 5901056);    // NN*64 halves -> [5901056, 9101056)
    __half* w1frag        = (__half*)(ws + 9101056);    // 8192 halves  -> [9101056, 9105152)
    __half* w2frag        = (__half*)(ws + 9105152);    // 3072 halves  -> [9105152, 9106688)
    __half* hw2h          = xw1h;                       // alias: xw1h dead after k_agg1; NN*40 halves fits
    // total: 9,106,688 floats = 36.4 MB

    k_wprep    <<<6, 256, 0, stream>>>(W1, W2, w1frag, w2frag);
    kA_zero    <<<1, 256, 0, stream>>>(bucket_cnt);
    kA_hist    <<<1024, 256, 0, stream>>>(dst, bucket_cnt);
    kA_scanb   <<<1, 256, 0, stream>>>(bucket_cnt, bucket_offs, bucket_cursor);
    kA_scatter <<<(EE + CH - 1) / CH, 256, 0, stream>>>(src, dst, bucket_cursor, ebuf);
    kB_csr     <<<NB, 256, 0, stream>>>(ebuf, bucket_offs, offs, dinv, esrc);
    k_gemm1    <<<(NN + 63) / 64, 256, 0, stream>>>(x, w1frag, dinv, xw1h);
    k_agg1     <<<(NN + 15) / 16, 256, 0, stream>>>(xw1h, dinv, offs, esrc, agg1h);
    k_gemm2    <<<(NN + 63) / 64, 256, 0, stream>>>(agg1h, b1, w2frag, dinv, hw2h);
    k_agg2     <<<(NN + 23) / 24, 256, 0, stream>>>(hw2h, dinv, offs, esrc, b2, out);
}

// Round 11
// 230.445 us; speedup vs baseline: 3.3734x; 1.0161x over previous
//
#include <hip/hip_runtime.h>
#include <hip/hip_fp16.h>

#define NN   100000
#define EE   1250000
#define DIN  128
#define HID  64
#define DOUT 40

#define BN   512                  // nodes per bucket
#define NB   196                  // ceil(NN/BN)
#define CH   4096                 // edges per scatter block (16/thread)

struct __align__(8) h4 { __half2 a, b; };   // 4 halves, one dwordx2 load

typedef _Float16 v8h __attribute__((ext_vector_type(8)));
typedef float    v4f __attribute__((ext_vector_type(4)));

// ---------------- CSR construction (bucketed, write-friendly) ----------------

__global__ __launch_bounds__(256) void kA_hist(const int* __restrict__ dst,
                                               int* __restrict__ bucket_cnt) {
    __shared__ int h[NB];
    int t = threadIdx.x;
    for (int i = t; i < NB; i += 256) h[i] = 0;
    __syncthreads();
    int stride = gridDim.x * 256;
    for (int e = blockIdx.x * 256 + t; e < EE; e += stride)
        atomicAdd(&h[dst[e] >> 9], 1);
    __syncthreads();
    for (int i = t; i < NB; i += 256)
        if (h[i]) atomicAdd(&bucket_cnt[i], h[i]);
}

__global__ __launch_bounds__(256) void kA_scanb(const int* __restrict__ bucket_cnt,
                                                int* __restrict__ bucket_offs,
                                                int* __restrict__ bucket_cursor) {
    __shared__ int a[256], b[256];
    int t = threadIdx.x;
    int v = (t < NB) ? bucket_cnt[t] : 0;
    a[t] = v;
    __syncthreads();
    int* s = a; int* d = b;
    for (int off = 1; off < 256; off <<= 1) {
        d[t] = s[t] + ((t >= off) ? s[t - off] : 0);
        __syncthreads();
        int* tmp = s; s = d; d = tmp;
    }
    int incl = s[t];
    if (t < NB) {
        bucket_offs[t]   = incl - v;
        bucket_cursor[t] = incl - v;
    }
    if (t == NB - 1) bucket_offs[NB] = incl;   // == EE
}

__global__ __launch_bounds__(256) void kA_scatter(const int* __restrict__ src,
                                                  const int* __restrict__ dst,
                                                  int* __restrict__ bucket_cursor,
                                                  int* __restrict__ ebuf) {
    __shared__ int hist[NB], gbase[NB], rcur[NB];
    int t = threadIdx.x;
    for (int i = t; i < NB; i += 256) { hist[i] = 0; rcur[i] = 0; }
    __syncthreads();
    int e0 = blockIdx.x * CH;
    int ep[16], eb[16];
    #pragma unroll
    for (int j = 0; j < 16; ++j) {
        int e = e0 + j * 256 + t;
        bool valid = (e < EE);
        if (valid) {
            int dd_ = dst[e];
            ep[j] = (src[e] << 9) | (dd_ & 511);
            eb[j] = dd_ >> 9;
            atomicAdd(&hist[eb[j]], 1);
        } else {
            ep[j] = 0; eb[j] = -1;
        }
    }
    __syncthreads();
    for (int i = t; i < NB; i += 256)
        gbase[i] = atomicAdd(&bucket_cursor[i], hist[i]);
    __syncthreads();
    #pragma unroll
    for (int j = 0; j < 16; ++j) {
        if (eb[j] >= 0) {
            int r = atomicAdd(&rcur[eb[j]], 1);
            ebuf[gbase[eb[j]] + r] = ep[j];
        }
    }
}

__global__ __launch_bounds__(256) void kB_csr(const int* __restrict__ ebuf,
                                              const int* __restrict__ bucket_offs,
                                              int* __restrict__ offs,
                                              float* __restrict__ dinv,
                                              int* __restrict__ esrc) {
    __shared__ int lcnt[BN], sA[BN], sB[BN], lcur[BN];
    int t = threadIdx.x;
    int b = blockIdx.x;
    lcnt[t] = 0; lcnt[t + 256] = 0;
    __syncthreads();
    int ebeg = bucket_offs[b], eend = bucket_offs[b + 1];
    for (int j = ebeg + t; j < eend; j += 256)
        atomicAdd(&lcnt[ebuf[j] & 511], 1);
    __syncthreads();
    sA[t] = lcnt[t]; sA[t + 256] = lcnt[t + 256];
    __syncthreads();
    int* s = sA; int* d = sB;
    for (int off = 1; off < BN; off <<= 1) {
        d[t] = s[t] + ((t >= off) ? s[t - off] : 0);
        int i2 = t + 256;
        d[i2] = s[i2] + ((i2 >= off) ? s[i2 - off] : 0);
        __syncthreads();
        int* tmp = s; s = d; d = tmp;
    }
    int base_node = b * BN;
    #pragma unroll
    for (int k = 0; k < 2; ++k) {
        int i = t + k * 256;
        int excl = s[i] - lcnt[i];
        lcur[i] = excl;
        int node = base_node + i;
        if (node < NN) {
            offs[node] = ebeg + excl;
            dinv[node] = rsqrtf((float)lcnt[i] + 1.0f);   // +1 self-loop
        }
    }
    if (b == NB - 1 && t == 0) offs[NN] = EE;
    __syncthreads();
    for (int j = ebeg + t; j < eend; j += 256) {
        int p = ebuf[j];
        int r = atomicAdd(&lcur[p & 511], 1);
        esrc[ebeg + r] = p >> 9;   // scattered only within this block's segment
    }
}

// ---------------- W1 & W2 -> B-fragment pre-pack + bucket_cnt zero ----------------
__global__ __launch_bounds__(256) void k_wprep(const float* __restrict__ W1,
                                               const float* __restrict__ W2,
                                               __half* __restrict__ w1frag,
                                               __half* __restrict__ w2frag,
                                               int* __restrict__ bucket_cnt) {
    int t = threadIdx.x;
    if (blockIdx.x == 5 && t < NB) bucket_cnt[t] = 0;   // fold kA_zero here
    int e = blockIdx.x * 256 + t;
    if (e < 1024) {
        int ct = e >> 8, ki = (e >> 6) & 3, l = e & 63;
        int q = l >> 4, n = l & 15;
        v8h o;
        #pragma unroll
        for (int j = 0; j < 8; ++j)
            o[j] = (_Float16)W1[(ki * 32 + q * 8 + j) * 64 + ct * 16 + n];
        ((v8h*)w1frag)[e] = o;
    } else {
        int e2 = e - 1024;
        if (e2 < 384) {
            int ct = e2 >> 7, ki = (e2 >> 6) & 1, l = e2 & 63;
            int q = l >> 4, n = l & 15;
            int col = ct * 16 + n;
            v8h o;
            #pragma unroll
            for (int j = 0; j < 8; ++j)
                o[j] = (col < DOUT) ? (_Float16)W2[(ki * 32 + q * 8 + j) * DOUT + col]
                                    : (_Float16)0.0f;
            ((v8h*)w2frag)[e2] = o;
        }
    }
}

// ---------------- layer 1 GEMM via MFMA: xw1h = fp16(dinv * (x @ W1)) ----------------
__global__ __launch_bounds__(256) void k_gemm1(const float* __restrict__ x,
                                               const __half* __restrict__ w1frag,
                                               const float* __restrict__ dinv,
                                               __half* __restrict__ xw1h) {
    __shared__ float4 sb4[1024];        // 16 KB: 16 frags x 64 lanes x 16 B
    int t = threadIdx.x;
    const float4* wf = (const float4*)w1frag;
    #pragma unroll
    for (int i = 0; i < 4; ++i) sb4[t + i * 256] = wf[t + i * 256];
    __syncthreads();
    const v8h* sbh = (const v8h*)sb4;

    int wv = t >> 6, l = t & 63;
    int q = l >> 4, n = l & 15;
    int row0 = blockIdx.x * 64 + wv * 16;
    int m = row0 + n;                   // A-operand row for this lane
    bool mv = (m < NN);
    const float* xr = x + (size_t)(mv ? m : 0) * DIN + q * 8;
    v8h afrag[4];
    #pragma unroll
    for (int ki = 0; ki < 4; ++ki) {
        float4 u0 = mv ? ((const float4*)(xr + ki * 32))[0] : make_float4(0.f,0.f,0.f,0.f);
        float4 u1 = mv ? ((const float4*)(xr + ki * 32))[1] : make_float4(0.f,0.f,0.f,0.f);
        v8h a;
        a[0] = (_Float16)u0.x; a[1] = (_Float16)u0.y;
        a[2] = (_Float16)u0.z; a[3] = (_Float16)u0.w;
        a[4] = (_Float16)u1.x; a[5] = (_Float16)u1.y;
        a[6] = (_Float16)u1.z; a[7] = (_Float16)u1.w;
        afrag[ki] = a;
    }
    v4f acc[4];
    #pragma unroll
    for (int ct = 0; ct < 4; ++ct) acc[ct] = (v4f){0.f, 0.f, 0.f, 0.f};
    #pragma unroll
    for (int ct = 0; ct < 4; ++ct) {
        #pragma unroll
        for (int ki = 0; ki < 4; ++ki)
            acc[ct] = __builtin_amdgcn_mfma_f32_16x16x32_f16(
                afrag[ki], sbh[(ct * 4 + ki) * 64 + l], acc[ct], 0, 0, 0);
    }
    _Float16* outh = (_Float16*)xw1h;
    #pragma unroll
    for (int r = 0; r < 4; ++r) {
        int rr = row0 + q * 4 + r;
        if (rr < NN) {
            float di = dinv[rr];
            #pragma unroll
            for (int ct = 0; ct < 4; ++ct)
                outh[(size_t)rr * HID + ct * 16 + n] = (_Float16)(acc[ct][r] * di);
        }
    }
}

// ---------------- fused: layer-1 aggregation (LDS) + layer-2 GEMM (MFMA) ----------------
// block = 64 dsts. Phase A: 16 groups x 16 lanes gather-aggregate 4 dsts each
// into LDS rows (fp16, stride 72 halves -> <=2-way bank aliasing = free).
// Phase B: 4 waves x 16 rows, A-frags from LDS (+bias+relu), 6 MFMAs.
// Output rows padded to 64 halves; cols 0..47 written (40..47 zero), 48..63
// left stale -- k_agg2 only uses cols < 40.
__global__ __launch_bounds__(256) void k_fuse(const __half* __restrict__ xw1h,
                                              const float* __restrict__ dinv,
                                              const int* __restrict__ offs,
                                              const int* __restrict__ esrc,
                                              const float* __restrict__ b1,
                                              const __half* __restrict__ w2frag,
                                              __half* __restrict__ hw2p) {
    __shared__ float4 sb4[384];          // 6 KB: W2 B-frags
    __shared__ __half sh[64 * 72];       // 9 KB: agg rows, padded stride
    __shared__ float sb1[64];
    int t = threadIdx.x;
    const float4* wf = (const float4*)w2frag;
    if (t < 192) { sb4[t] = wf[t]; sb4[t + 192] = wf[t + 192]; }
    if (t >= 192) sb1[t - 192] = b1[t - 192];
    int d0 = blockIdx.x * 64;
    int g = t >> 4, q = t & 15;
    const h4* table = (const h4*)xw1h;
    #pragma unroll
    for (int sub = 0; sub < 4; ++sub) {
        int d = d0 + g * 4 + sub;
        if (d < NN) {
            h4 v = table[(unsigned)d * 16u + q];   // self-loop
            float2 f0 = __half22float2(v.a), f1 = __half22float2(v.b);
            float4 acc = make_float4(f0.x, f0.y, f1.x, f1.y);
            int j = offs[d], je = offs[d + 1];
            for (; j + 7 < je; j += 8) {
                int ss[8];
                #pragma unroll
                for (int u = 0; u < 8; ++u) ss[u] = esrc[j + u];
                h4 vv[8];
                #pragma unroll
                for (int u = 0; u < 8; ++u) vv[u] = table[(unsigned)ss[u] * 16u + q];
                #pragma unroll
                for (int u = 0; u < 8; ++u) {
                    float2 a = __half22float2(vv[u].a), c = __half22float2(vv[u].b);
                    acc.x += a.x; acc.y += a.y; acc.z += c.x; acc.w += c.y;
                }
            }
            for (; j + 3 < je; j += 4) {
                int s0 = esrc[j], s1 = esrc[j + 1], s2 = esrc[j + 2], s3 = esrc[j + 3];
                h4 v0 = table[(unsigned)s0 * 16u + q];
                h4 v1 = table[(unsigned)s1 * 16u + q];
                h4 v2 = table[(unsigned)s2 * 16u + q];
                h4 v3 = table[(unsigned)s3 * 16u + q];
                float2 a0 = __half22float2(v0.a), c0 = __half22float2(v0.b);
                float2 a1 = __half22float2(v1.a), c1 = __half22float2(v1.b);
                float2 a2 = __half22float2(v2.a), c2 = __half22float2(v2.b);
                float2 a3 = __half22float2(v3.a), c3 = __half22float2(v3.b);
                acc.x += (a0.x + a1.x) + (a2.x + a3.x);
                acc.y += (a0.y + a1.y) + (a2.y + a3.y);
                acc.z += (c0.x + c1.x) + (c2.x + c3.x);
                acc.w += (c0.y + c1.y) + (c2.y + c3.y);
            }
            for (; j < je; ++j) {
                h4 vv = table[(unsigned)esrc[j] * 16u + q];
                float2 a = __half22float2(vv.a), c = __half22float2(vv.b);
                acc.x += a.x; acc.y += a.y; acc.z += c.x; acc.w += c.y;
            }
            float dd = dinv[d];
            h4 o;
            o.a = __floats2half2_rn(dd * acc.x, dd * acc.y);
            o.b = __floats2half2_rn(dd * acc.z, dd * acc.w);
            ((h4*)(sh + (g * 4 + sub) * 72))[q] = o;
        }
    }
    __syncthreads();
    // phase B
    const v8h* sbh = (const v8h*)sb4;
    int wv = t >> 6, l = t & 63;
    int qq = l >> 4, n = l & 15;
    int srow = wv * 16 + n;              // A-operand LDS row (m = lane&15)
    v8h afrag[2];
    #pragma unroll
    for (int ki = 0; ki < 2; ++ki) {
        v8h a = *(const v8h*)(sh + srow * 72 + ki * 32 + qq * 8);
        #pragma unroll
        for (int j = 0; j < 8; ++j) {
            float av = (float)a[j] + sb1[ki * 32 + qq * 8 + j];
            a[j] = (_Float16)fmaxf(av, 0.f);
        }
        afrag[ki] = a;
    }
    v4f acc[3];
    #pragma unroll
    for (int ct = 0; ct < 3; ++ct) acc[ct] = (v4f){0.f, 0.f, 0.f, 0.f};
    #pragma unroll
    for (int ct = 0; ct < 3; ++ct) {
        #pragma unroll
        for (int ki = 0; ki < 2; ++ki)
            acc[ct] = __builtin_amdgcn_mfma_f32_16x16x32_f16(
                afrag[ki], sbh[(ct * 2 + ki) * 64 + l], acc[ct], 0, 0, 0);
    }
    _Float16* outh = (_Float16*)hw2p;
    #pragma unroll
    for (int r = 0; r < 4; ++r) {
        int rr = d0 + wv * 16 + qq * 4 + r;
        if (rr < NN) {
            float di = dinv[rr];
            #pragma unroll
            for (int ct = 0; ct < 3; ++ct)
                outh[(size_t)rr * 64 + ct * 16 + n] = (_Float16)(acc[ct][r] * di);
        }
    }
}

// ---------------- layer 2 aggregation: 16-lane groups on padded 128-B rows ----------------
__global__ __launch_bounds__(256) void k_agg2(const __half* __restrict__ hw2p,
                                              const float* __restrict__ dinv,
                                              const int* __restrict__ offs,
                                              const int* __restrict__ esrc,
                                              const float* __restrict__ b2,
                                              float* __restrict__ out) {
    int t = threadIdx.x;
    int g = t >> 4, q = t & 15;         // lanes q>=10 compute discarded channels
    int d = blockIdx.x * 16 + g;
    if (d >= NN) return;
    const h4* table = (const h4*)hw2p;   // 16 h4 per padded row
    h4 v = table[(unsigned)d * 16u + q];   // self-loop term
    float2 f0 = __half22float2(v.a), f1 = __half22float2(v.b);
    float4 acc = make_float4(f0.x, f0.y, f1.x, f1.y);
    int j = offs[d], je = offs[d + 1];
    for (; j + 7 < je; j += 8) {
        int ss[8];
        #pragma unroll
        for (int u = 0; u < 8; ++u) ss[u] = esrc[j + u];
        h4 vv[8];
        #pragma unroll
        for (int u = 0; u < 8; ++u) vv[u] = table[(unsigned)ss[u] * 16u + q];
        #pragma unroll
        for (int u = 0; u < 8; ++u) {
            float2 a = __half22float2(vv[u].a), c = __half22float2(vv[u].b);
            acc.x += a.x; acc.y += a.y; acc.z += c.x; acc.w += c.y;
        }
    }
    for (; j + 3 < je; j += 4) {
        int s0 = esrc[j], s1 = esrc[j + 1], s2 = esrc[j + 2], s3 = esrc[j + 3];
        h4 v0 = table[(unsigned)s0 * 16u + q];
        h4 v1 = table[(unsigned)s1 * 16u + q];
        h4 v2 = table[(unsigned)s2 * 16u + q];
        h4 v3 = table[(unsigned)s3 * 16u + q];
        float2 a0 = __half22float2(v0.a), c0 = __half22float2(v0.b);
        float2 a1 = __half22float2(v1.a), c1 = __half22float2(v1.b);
        float2 a2 = __half22float2(v2.a), c2 = __half22float2(v2.b);
        float2 a3 = __half22float2(v3.a), c3 = __half22float2(v3.b);
        acc.x += (a0.x + a1.x) + (a2.x + a3.x);
        acc.y += (a0.y + a1.y) + (a2.y + a3.y);
        acc.z += (c0.x + c1.x) + (c2.x + c3.x);
        acc.w += (c0.y + c1.y) + (c2.y + c3.y);
    }
    for (; j < je; ++j) {
        h4 vv = table[(unsigned)esrc[j] * 16u + q];
        float2 a = __half22float2(vv.a), c = __half22float2(vv.b);
        acc.x += a.x; acc.y += a.y; acc.z += c.x; acc.w += c.y;
    }
    if (q < 10) {
        float dd = dinv[d];
        float4 bb = ((const float4*)b2)[q];
        ((float4*)(out + (size_t)d * DOUT))[q] =
            make_float4(dd * acc.x + bb.x, dd * acc.y + bb.y,
                        dd * acc.z + bb.z, dd * acc.w + bb.w);
    }
}

extern "C" void kernel_launch(void* const* d_in, const int* in_sizes, int n_in,
                              void* d_out, int out_size, void* d_ws, size_t ws_size,
                              hipStream_t stream) {
    const float* x  = (const float*)d_in[0];
    const float* W1 = (const float*)d_in[1];
    const float* b1 = (const float*)d_in[2];
    const float* W2 = (const float*)d_in[3];
    const float* b2 = (const float*)d_in[4];
    const int*   ei = (const int*)d_in[5];
    const int* src = ei;        // edge_index[0]
    const int* dst = ei + EE;   // edge_index[1]
    float* out = (float*)d_out;

    float* ws = (float*)d_ws;
    int*    bucket_cnt    = (int*)ws;                   // [0,256)
    int*    bucket_offs   = (int*)ws + 256;             // [256,512) NB+1 used
    int*    bucket_cursor = (int*)ws + 512;             // [512,768)
    int*    offs          = (int*)ws + 1024;            // NN+1
    float*  dinv          = ws + 101056;                // NN
    int*    esrc          = (int*)ws + 201056;          // EE
    int*    ebuf          = (int*)ws + 1451056;         // EE packed
    __half* xw1h          = (__half*)(ws + 2701056);    // NN*64 halves -> [2701056, 5901056)
    __half* hw2p          = (__half*)(ws + 5901056);    // NN*64 halves (padded rows) -> [5901056, 9101056)
    __half* w1frag        = (__half*)(ws + 9101056);    // 8192 halves
    __half* w2frag        = (__half*)(ws + 9105152);    // 3072 halves
    // total: 9,106,688 floats = 36.4 MB

    k_wprep    <<<6, 256, 0, stream>>>(W1, W2, w1frag, w2frag, bucket_cnt);
    kA_hist    <<<1024, 256, 0, stream>>>(dst, bucket_cnt);
    kA_scanb   <<<1, 256, 0, stream>>>(bucket_cnt, bucket_offs, bucket_cursor);
    kA_scatter <<<(EE + CH - 1) / CH, 256, 0, stream>>>(src, dst, bucket_cursor, ebuf);
    kB_csr     <<<NB, 256, 0, stream>>>(ebuf, bucket_offs, offs, dinv, esrc);
    k_gemm1    <<<(NN + 63) / 64, 256, 0, stream>>>(x, w1frag, dinv, xw1h);
    k_fuse     <<<(NN + 63) / 64, 256, 0, stream>>>(xw1h, dinv, offs, esrc, b1, w2frag, hw2p);
    k_agg2     <<<(NN + 15) / 16, 256, 0, stream>>>(hw2p, dinv, offs, esrc, b2, out);
}

// Round 12
// 200.544 us; speedup vs baseline: 3.8764x; 1.1491x over previous
//
#include <hip/hip_runtime.h>
#include <hip/hip_fp16.h>

#define NN   100000
#define EE   1250000
#define DIN  128
#define HID  64
#define DOUT 40

#define BN   512                  // nodes per bucket
#define NB   196                  // ceil(NN/BN)
#define CH   4096                 // edges per scatter block (16/thread)
#define SEG  8192                 // padded bucket capacity (mean 6377, 22 sigma)
#define S_BLKS 306                // ceil(EE/CH)
#define G_BLKS 1563               // ceil(NN/64)

struct __align__(8) h4 { __half2 a, b; };   // 4 halves, one dwordx2 load

typedef _Float16 v8h __attribute__((ext_vector_type(8)));
typedef float    v4f __attribute__((ext_vector_type(4)));

// ---------------- W1 & W2 -> B-fragment pre-pack + bucket_fill zero ----------------
__global__ __launch_bounds__(256) void k_wprep(const float* __restrict__ W1,
                                               const float* __restrict__ W2,
                                               __half* __restrict__ w1frag,
                                               __half* __restrict__ w2frag,
                                               int* __restrict__ bucket_fill) {
    int t = threadIdx.x;
    if (blockIdx.x == 5 && t < NB) bucket_fill[t] = 0;
    int e = blockIdx.x * 256 + t;
    if (e < 1024) {
        int ct = e >> 8, ki = (e >> 6) & 3, l = e & 63;
        int q = l >> 4, n = l & 15;
        v8h o;
        #pragma unroll
        for (int j = 0; j < 8; ++j)
            o[j] = (_Float16)W1[(ki * 32 + q * 8 + j) * 64 + ct * 16 + n];
        ((v8h*)w1frag)[e] = o;
    } else {
        int e2 = e - 1024;
        if (e2 < 384) {
            int ct = e2 >> 7, ki = (e2 >> 6) & 1, l = e2 & 63;
            int q = l >> 4, n = l & 15;
            int col = ct * 16 + n;
            v8h o;
            #pragma unroll
            for (int j = 0; j < 8; ++j)
                o[j] = (col < DOUT) ? (_Float16)W2[(ki * 32 + q * 8 + j) * DOUT + col]
                                    : (_Float16)0.0f;
            ((v8h*)w2frag)[e2] = o;
        }
    }
}

// ---------------- fat kernel: edge scatter (blocks < S_BLKS) || gemm1 (rest) ----------------
// scatter: single-pass bucketing into padded SEG segments via bucket_fill atomics.
// gemm1: MFMA x@W1 -> xw1h UNSCALED (dinv applied later in kB_csr).
__global__ __launch_bounds__(256) void k_fat(const int* __restrict__ src,
                                             const int* __restrict__ dst,
                                             int* __restrict__ bucket_fill,
                                             int* __restrict__ ebuf,
                                             const float* __restrict__ x,
                                             const __half* __restrict__ w1frag,
                                             __half* __restrict__ xw1h) {
    __shared__ int smem[4096];           // 16 KB union
    int t = threadIdx.x;
    if (blockIdx.x < S_BLKS) {
        int* hist  = smem;
        int* gbase = smem + 256;
        int* rcur  = smem + 512;
        for (int i = t; i < NB; i += 256) { hist[i] = 0; rcur[i] = 0; }
        __syncthreads();
        int e0 = blockIdx.x * CH;
        int ep[16], eb[16];
        #pragma unroll
        for (int j = 0; j < 16; ++j) {
            int e = e0 + j * 256 + t;
            bool valid = (e < EE);
            if (valid) {
                int dd_ = dst[e];
                ep[j] = (src[e] << 9) | (dd_ & 511);
                eb[j] = dd_ >> 9;
                atomicAdd(&hist[eb[j]], 1);
            } else {
                ep[j] = 0; eb[j] = -1;
            }
        }
        __syncthreads();
        for (int i = t; i < NB; i += 256)
            gbase[i] = atomicAdd(&bucket_fill[i], hist[i]);
        __syncthreads();
        #pragma unroll
        for (int j = 0; j < 16; ++j) {
            if (eb[j] >= 0) {
                int r = atomicAdd(&rcur[eb[j]], 1);
                ebuf[eb[j] * SEG + gbase[eb[j]] + r] = ep[j];
            }
        }
    } else {
        float4* sb4 = (float4*)smem;     // 1024 float4 = 16 KB
        const float4* wf = (const float4*)w1frag;
        #pragma unroll
        for (int i = 0; i < 4; ++i) sb4[t + i * 256] = wf[t + i * 256];
        __syncthreads();
        const v8h* sbh = (const v8h*)sb4;
        int wv = t >> 6, l = t & 63;
        int q = l >> 4, n = l & 15;
        int row0 = (blockIdx.x - S_BLKS) * 64 + wv * 16;
        int m = row0 + n;
        bool mv = (m < NN);
        const float* xr = x + (size_t)(mv ? m : 0) * DIN + q * 8;
        v8h afrag[4];
        #pragma unroll
        for (int ki = 0; ki < 4; ++ki) {
            float4 u0 = mv ? ((const float4*)(xr + ki * 32))[0] : make_float4(0.f,0.f,0.f,0.f);
            float4 u1 = mv ? ((const float4*)(xr + ki * 32))[1] : make_float4(0.f,0.f,0.f,0.f);
            v8h a;
            a[0] = (_Float16)u0.x; a[1] = (_Float16)u0.y;
            a[2] = (_Float16)u0.z; a[3] = (_Float16)u0.w;
            a[4] = (_Float16)u1.x; a[5] = (_Float16)u1.y;
            a[6] = (_Float16)u1.z; a[7] = (_Float16)u1.w;
            afrag[ki] = a;
        }
        v4f acc[4];
        #pragma unroll
        for (int ct = 0; ct < 4; ++ct) acc[ct] = (v4f){0.f, 0.f, 0.f, 0.f};
        #pragma unroll
        for (int ct = 0; ct < 4; ++ct) {
            #pragma unroll
            for (int ki = 0; ki < 4; ++ki)
                acc[ct] = __builtin_amdgcn_mfma_f32_16x16x32_f16(
                    afrag[ki], sbh[(ct * 4 + ki) * 64 + l], acc[ct], 0, 0, 0);
        }
        _Float16* outh = (_Float16*)xw1h;
        #pragma unroll
        for (int r = 0; r < 4; ++r) {
            int rr = row0 + q * 4 + r;
            if (rr < NN) {
                #pragma unroll
                for (int ct = 0; ct < 4; ++ct)
                    outh[(size_t)rr * HID + ct * 16 + n] = (_Float16)acc[ct][r];
            }
        }
    }
}

// ---------------- per-bucket CSR + dinv + xw1h scaling ----------------
// pofs[node] = (global_start << 10) | count; esrc in same padded segments.
__global__ __launch_bounds__(256) void kB_csr(const int* __restrict__ ebuf,
                                              const int* __restrict__ bucket_fill,
                                              int* __restrict__ pofs,
                                              float* __restrict__ dinv,
                                              int* __restrict__ esrc,
                                              __half* __restrict__ xw1h) {
    __shared__ int lcnt[BN], sA[BN], sB[BN], lcur[BN];
    int t = threadIdx.x;
    int b = blockIdx.x;
    int eb0 = b * SEG;
    int ecnt = bucket_fill[b];
    lcnt[t] = 0; lcnt[t + 256] = 0;
    __syncthreads();
    for (int j = t; j < ecnt; j += 256)
        atomicAdd(&lcnt[ebuf[eb0 + j] & 511], 1);
    __syncthreads();
    sA[t] = lcnt[t]; sA[t + 256] = lcnt[t + 256];
    __syncthreads();
    int* s = sA; int* d = sB;
    for (int off = 1; off < BN; off <<= 1) {
        d[t] = s[t] + ((t >= off) ? s[t - off] : 0);
        int i2 = t + 256;
        d[i2] = s[i2] + ((i2 >= off) ? s[i2 - off] : 0);
        __syncthreads();
        int* tmp = s; s = d; d = tmp;
    }
    int base_node = b * BN;
    #pragma unroll
    for (int k = 0; k < 2; ++k) {
        int i = t + k * 256;
        int excl = s[i] - lcnt[i];
        lcur[i] = excl;
        int node = base_node + i;
        if (node < NN) {
            pofs[node] = ((eb0 + excl) << 10) | lcnt[i];
            dinv[node] = rsqrtf((float)lcnt[i] + 1.0f);   // +1 self-loop
        }
    }
    __syncthreads();
    for (int j = t; j < ecnt; j += 256) {
        int p = ebuf[eb0 + j];
        int r = atomicAdd(&lcur[p & 511], 1);
        esrc[eb0 + r] = p >> 9;
    }
    // scale this bucket's xw1h rows by dinv (k_fat wrote them unscaled)
    float4* xr4 = (float4*)xw1h;
    for (int i = t; i < BN * 8; i += 256) {
        int li = i >> 3;
        int node = base_node + li;
        if (node < NN) {
            float di = rsqrtf((float)lcnt[li] + 1.0f);
            float4 v = xr4[(size_t)node * 8 + (i & 7)];
            __half2* h = (__half2*)&v;
            #pragma unroll
            for (int u = 0; u < 4; ++u) {
                float2 f = __half22float2(h[u]);
                h[u] = __floats2half2_rn(f.x * di, f.y * di);
            }
            xr4[(size_t)node * 8 + (i & 7)] = v;
        }
    }
}

// ---------------- fused: layer-1 aggregation (LDS) + layer-2 GEMM (MFMA) ----------------
__global__ __launch_bounds__(256) void k_fuse(const __half* __restrict__ xw1h,
                                              const float* __restrict__ dinv,
                                              const int* __restrict__ pofs,
                                              const int* __restrict__ esrc,
                                              const float* __restrict__ b1,
                                              const __half* __restrict__ w2frag,
                                              __half* __restrict__ hw2p) {
    __shared__ float4 sb4[384];          // 6 KB: W2 B-frags
    __shared__ __half sh[64 * 72];       // 9 KB: agg rows, padded stride
    __shared__ float sb1[64];
    int t = threadIdx.x;
    const float4* wf = (const float4*)w2frag;
    if (t < 192) { sb4[t] = wf[t]; sb4[t + 192] = wf[t + 192]; }
    if (t >= 192) sb1[t - 192] = b1[t - 192];
    int d0 = blockIdx.x * 64;
    int g = t >> 4, q = t & 15;
    const h4* table = (const h4*)xw1h;
    #pragma unroll
    for (int sub = 0; sub < 4; ++sub) {
        int d = d0 + g * 4 + sub;
        if (d < NN) {
            h4 v = table[(unsigned)d * 16u + q];   // self-loop
            float2 f0 = __half22float2(v.a), f1 = __half22float2(v.b);
            float4 acc = make_float4(f0.x, f0.y, f1.x, f1.y);
            int p = pofs[d];
            int j = p >> 10, je = j + (p & 1023);
            for (; j + 7 < je; j += 8) {
                int ss[8];
                #pragma unroll
                for (int u = 0; u < 8; ++u) ss[u] = esrc[j + u];
                h4 vv[8];
                #pragma unroll
                for (int u = 0; u < 8; ++u) vv[u] = table[(unsigned)ss[u] * 16u + q];
                #pragma unroll
                for (int u = 0; u < 8; ++u) {
                    float2 a = __half22float2(vv[u].a), c = __half22float2(vv[u].b);
                    acc.x += a.x; acc.y += a.y; acc.z += c.x; acc.w += c.y;
                }
            }
            for (; j + 3 < je; j += 4) {
                int s0 = esrc[j], s1 = esrc[j + 1], s2 = esrc[j + 2], s3 = esrc[j + 3];
                h4 v0 = table[(unsigned)s0 * 16u + q];
                h4 v1 = table[(unsigned)s1 * 16u + q];
                h4 v2 = table[(unsigned)s2 * 16u + q];
                h4 v3 = table[(unsigned)s3 * 16u + q];
                float2 a0 = __half22float2(v0.a), c0 = __half22float2(v0.b);
                float2 a1 = __half22float2(v1.a), c1 = __half22float2(v1.b);
                float2 a2 = __half22float2(v2.a), c2 = __half22float2(v2.b);
                float2 a3 = __half22float2(v3.a), c3 = __half22float2(v3.b);
                acc.x += (a0.x + a1.x) + (a2.x + a3.x);
                acc.y += (a0.y + a1.y) + (a2.y + a3.y);
                acc.z += (c0.x + c1.x) + (c2.x + c3.x);
                acc.w += (c0.y + c1.y) + (c2.y + c3.y);
            }
            for (; j < je; ++j) {
                h4 vv = table[(unsigned)esrc[j] * 16u + q];
                float2 a = __half22float2(vv.a), c = __half22float2(vv.b);
                acc.x += a.x; acc.y += a.y; acc.z += c.x; acc.w += c.y;
            }
            float dd = dinv[d];
            h4 o;
            o.a = __floats2half2_rn(dd * acc.x, dd * acc.y);
            o.b = __floats2half2_rn(dd * acc.z, dd * acc.w);
            ((h4*)(sh + (g * 4 + sub) * 72))[q] = o;
        }
    }
    __syncthreads();
    // phase B: 4 waves x 16 rows, A from LDS (+bias+relu), 6 MFMAs
    const v8h* sbh = (const v8h*)sb4;
    int wv = t >> 6, l = t & 63;
    int qq = l >> 4, n = l & 15;
    int srow = wv * 16 + n;
    v8h afrag[2];
    #pragma unroll
    for (int ki = 0; ki < 2; ++ki) {
        v8h a = *(const v8h*)(sh + srow * 72 + ki * 32 + qq * 8);
        #pragma unroll
        for (int j = 0; j < 8; ++j) {
            float av = (float)a[j] + sb1[ki * 32 + qq * 8 + j];
            a[j] = (_Float16)fmaxf(av, 0.f);
        }
        afrag[ki] = a;
    }
    v4f acc[3];
    #pragma unroll
    for (int ct = 0; ct < 3; ++ct) acc[ct] = (v4f){0.f, 0.f, 0.f, 0.f};
    #pragma unroll
    for (int ct = 0; ct < 3; ++ct) {
        #pragma unroll
        for (int ki = 0; ki < 2; ++ki)
            acc[ct] = __builtin_amdgcn_mfma_f32_16x16x32_f16(
                afrag[ki], sbh[(ct * 2 + ki) * 64 + l], acc[ct], 0, 0, 0);
    }
    _Float16* outh = (_Float16*)hw2p;
    #pragma unroll
    for (int r = 0; r < 4; ++r) {
        int rr = d0 + wv * 16 + qq * 4 + r;
        if (rr < NN) {
            float di = dinv[rr];
            #pragma unroll
            for (int ct = 0; ct < 3; ++ct)
                outh[(size_t)rr * 64 + ct * 16 + n] = (_Float16)(acc[ct][r] * di);
        }
    }
}

// ---------------- layer 2 aggregation: 16-lane groups on padded 128-B rows ----------------
__global__ __launch_bounds__(256) void k_agg2(const __half* __restrict__ hw2p,
                                              const float* __restrict__ dinv,
                                              const int* __restrict__ pofs,
                                              const int* __restrict__ esrc,
                                              const float* __restrict__ b2,
                                              float* __restrict__ out) {
    int t = threadIdx.x;
    int g = t >> 4, q = t & 15;         // lanes q>=10 compute discarded channels
    int d = blockIdx.x * 16 + g;
    if (d >= NN) return;
    const h4* table = (const h4*)hw2p;   // 16 h4 per padded row
    h4 v = table[(unsigned)d * 16u + q];   // self-loop term
    float2 f0 = __half22float2(v.a), f1 = __half22float2(v.b);
    float4 acc = make_float4(f0.x, f0.y, f1.x, f1.y);
    int p = pofs[d];
    int j = p >> 10, je = j + (p & 1023);
    for (; j + 7 < je; j += 8) {
        int ss[8];
        #pragma unroll
        for (int u = 0; u < 8; ++u) ss[u] = esrc[j + u];
        h4 vv[8];
        #pragma unroll
        for (int u = 0; u < 8; ++u) vv[u] = table[(unsigned)ss[u] * 16u + q];
        #pragma unroll
        for (int u = 0; u < 8; ++u) {
            float2 a = __half22float2(vv[u].a), c = __half22float2(vv[u].b);
            acc.x += a.x; acc.y += a.y; acc.z += c.x; acc.w += c.y;
        }
    }
    for (; j + 3 < je; j += 4) {
        int s0 = esrc[j], s1 = esrc[j + 1], s2 = esrc[j + 2], s3 = esrc[j + 3];
        h4 v0 = table[(unsigned)s0 * 16u + q];
        h4 v1 = table[(unsigned)s1 * 16u + q];
        h4 v2 = table[(unsigned)s2 * 16u + q];
        h4 v3 = table[(unsigned)s3 * 16u + q];
        float2 a0 = __half22float2(v0.a), c0 = __half22float2(v0.b);
        float2 a1 = __half22float2(v1.a), c1 = __half22float2(v1.b);
        float2 a2 = __half22float2(v2.a), c2 = __half22float2(v2.b);
        float2 a3 = __half22float2(v3.a), c3 = __half22float2(v3.b);
        acc.x += (a0.x + a1.x) + (a2.x + a3.x);
        acc.y += (a0.y + a1.y) + (a2.y + a3.y);
        acc.z += (c0.x + c1.x) + (c2.x + c3.x);
        acc.w += (c0.y + c1.y) + (c2.y + c3.y);
    }
    for (; j < je; ++j) {
        h4 vv = table[(unsigned)esrc[j] * 16u + q];
        float2 a = __half22float2(vv.a), c = __half22float2(vv.b);
        acc.x += a.x; acc.y += a.y; acc.z += c.x; acc.w += c.y;
    }
    if (q < 10) {
        float dd = dinv[d];
        float4 bb = ((const float4*)b2)[q];
        ((float4*)(out + (size_t)d * DOUT))[q] =
            make_float4(dd * acc.x + bb.x, dd * acc.y + bb.y,
                        dd * acc.z + bb.z, dd * acc.w + bb.w);
    }
}

extern "C" void kernel_launch(void* const* d_in, const int* in_sizes, int n_in,
                              void* d_out, int out_size, void* d_ws, size_t ws_size,
                              hipStream_t stream) {
    const float* x  = (const float*)d_in[0];
    const float* W1 = (const float*)d_in[1];
    const float* b1 = (const float*)d_in[2];
    const float* W2 = (const float*)d_in[3];
    const float* b2 = (const float*)d_in[4];
    const int*   ei = (const int*)d_in[5];
    const int* src = ei;        // edge_index[0]
    const int* dst = ei + EE;   // edge_index[1]
    float* out = (float*)d_out;

    float* ws = (float*)d_ws;
    int*    bucket_fill = (int*)ws;                     // [0,256)
    int*    pofs        = (int*)ws + 256;               // NN -> [256, 100256)
    float*  dinv        = ws + 100352;                  // NN -> [100352, 200352)
    int*    ebuf        = (int*)ws + 200704;            // NB*SEG = 1605632 -> [200704, 1806336)
    int*    esrc        = (int*)ws + 1806336;           // NB*SEG -> [1806336, 3411968)
    __half* xw1h        = (__half*)(ws + 3411968);      // NN*64 halves -> [3411968, 6611968)
    __half* hw2p        = (__half*)(ws + 6611968);      // NN*64 halves (padded rows) -> [6611968, 9811968)
    __half* w1frag      = (__half*)(ws + 9811968);      // 8192 halves
    __half* w2frag      = (__half*)(ws + 9816064);      // 3072 halves
    // total: 9,817,600 floats = 39.3 MB

    k_wprep <<<6, 256, 0, stream>>>(W1, W2, w1frag, w2frag, bucket_fill);
    k_fat   <<<S_BLKS + G_BLKS, 256, 0, stream>>>(src, dst, bucket_fill, ebuf, x, w1frag, xw1h);
    kB_csr  <<<NB, 256, 0, stream>>>(ebuf, bucket_fill, pofs, dinv, esrc, xw1h);
    k_fuse  <<<(NN + 63) / 64, 256, 0, stream>>>(xw1h, dinv, pofs, esrc, b1, w2frag, hw2p);
    k_agg2  <<<(NN + 15) / 16, 256, 0, stream>>>(hw2p, dinv, pofs, esrc, b2, out);
}

// Round 13
// 199.701 us; speedup vs baseline: 3.8928x; 1.0042x over previous
//
#include <hip/hip_runtime.h>
#include <hip/hip_fp16.h>

#define NN   100000
#define EE   1250000
#define DIN  128
#define HID  64
#define DOUT 40

#define BN   512                  // nodes per bucket
#define NB   196                  // ceil(NN/BN)
#define CH   4096                 // edges per scatter block (16/thread)
#define SEG  8192                 // padded bucket capacity (mean 6377, 22 sigma)
#define S_BLKS 306                // ceil(EE/CH)
#define G_BLKS 1563               // ceil(NN/64)

typedef _Float16 v8h __attribute__((ext_vector_type(8)));
typedef float    v4f __attribute__((ext_vector_type(4)));

// unpack a float4-of-8-halves and accumulate into 2 float4s
__device__ __forceinline__ void acc8(const float4& v, float4& lo, float4& hi) {
    const __half2* hp = (const __half2*)&v;
    float2 f0 = __half22float2(hp[0]), f1 = __half22float2(hp[1]);
    float2 f2 = __half22float2(hp[2]), f3 = __half22float2(hp[3]);
    lo.x += f0.x; lo.y += f0.y; lo.z += f1.x; lo.w += f1.y;
    hi.x += f2.x; hi.y += f2.y; hi.z += f3.x; hi.w += f3.y;
}

// ---------------- W1 & W2 -> B-fragment pre-pack + bucket_fill zero ----------------
__global__ __launch_bounds__(256) void k_wprep(const float* __restrict__ W1,
                                               const float* __restrict__ W2,
                                               __half* __restrict__ w1frag,
                                               __half* __restrict__ w2frag,
                                               int* __restrict__ bucket_fill) {
    int t = threadIdx.x;
    if (blockIdx.x == 5 && t < NB) bucket_fill[t] = 0;
    int e = blockIdx.x * 256 + t;
    if (e < 1024) {
        int ct = e >> 8, ki = (e >> 6) & 3, l = e & 63;
        int q = l >> 4, n = l & 15;
        v8h o;
        #pragma unroll
        for (int j = 0; j < 8; ++j)
            o[j] = (_Float16)W1[(ki * 32 + q * 8 + j) * 64 + ct * 16 + n];
        ((v8h*)w1frag)[e] = o;
    } else {
        int e2 = e - 1024;
        if (e2 < 384) {
            int ct = e2 >> 7, ki = (e2 >> 6) & 1, l = e2 & 63;
            int q = l >> 4, n = l & 15;
            int col = ct * 16 + n;
            v8h o;
            #pragma unroll
            for (int j = 0; j < 8; ++j)
                o[j] = (col < DOUT) ? (_Float16)W2[(ki * 32 + q * 8 + j) * DOUT + col]
                                    : (_Float16)0.0f;
            ((v8h*)w2frag)[e2] = o;
        }
    }
}

// ---------------- fat kernel: edge scatter (blocks < S_BLKS) || gemm1 (rest) ----------------
__global__ __launch_bounds__(256) void k_fat(const int* __restrict__ src,
                                             const int* __restrict__ dst,
                                             int* __restrict__ bucket_fill,
                                             int* __restrict__ ebuf,
                                             const float* __restrict__ x,
                                             const __half* __restrict__ w1frag,
                                             __half* __restrict__ xw1h) {
    __shared__ int smem[4096];           // 16 KB union
    int t = threadIdx.x;
    if (blockIdx.x < S_BLKS) {
        int* hist  = smem;
        int* gbase = smem + 256;
        int* rcur  = smem + 512;
        for (int i = t; i < NB; i += 256) { hist[i] = 0; rcur[i] = 0; }
        __syncthreads();
        int e0 = blockIdx.x * CH;
        int ep[16], eb[16];
        #pragma unroll
        for (int j = 0; j < 16; ++j) {
            int e = e0 + j * 256 + t;
            bool valid = (e < EE);
            if (valid) {
                int dd_ = dst[e];
                ep[j] = (src[e] << 9) | (dd_ & 511);
                eb[j] = dd_ >> 9;
                atomicAdd(&hist[eb[j]], 1);
            } else {
                ep[j] = 0; eb[j] = -1;
            }
        }
        __syncthreads();
        for (int i = t; i < NB; i += 256)
            gbase[i] = atomicAdd(&bucket_fill[i], hist[i]);
        __syncthreads();
        #pragma unroll
        for (int j = 0; j < 16; ++j) {
            if (eb[j] >= 0) {
                int r = atomicAdd(&rcur[eb[j]], 1);
                ebuf[eb[j] * SEG + gbase[eb[j]] + r] = ep[j];
            }
        }
    } else {
        float4* sb4 = (float4*)smem;     // 1024 float4 = 16 KB
        const float4* wf = (const float4*)w1frag;
        #pragma unroll
        for (int i = 0; i < 4; ++i) sb4[t + i * 256] = wf[t + i * 256];
        __syncthreads();
        const v8h* sbh = (const v8h*)sb4;
        int wv = t >> 6, l = t & 63;
        int q = l >> 4, n = l & 15;
        int row0 = (blockIdx.x - S_BLKS) * 64 + wv * 16;
        int m = row0 + n;
        bool mv = (m < NN);
        const float* xr = x + (size_t)(mv ? m : 0) * DIN + q * 8;
        v8h afrag[4];
        #pragma unroll
        for (int ki = 0; ki < 4; ++ki) {
            float4 u0 = mv ? ((const float4*)(xr + ki * 32))[0] : make_float4(0.f,0.f,0.f,0.f);
            float4 u1 = mv ? ((const float4*)(xr + ki * 32))[1] : make_float4(0.f,0.f,0.f,0.f);
            v8h a;
            a[0] = (_Float16)u0.x; a[1] = (_Float16)u0.y;
            a[2] = (_Float16)u0.z; a[3] = (_Float16)u0.w;
            a[4] = (_Float16)u1.x; a[5] = (_Float16)u1.y;
            a[6] = (_Float16)u1.z; a[7] = (_Float16)u1.w;
            afrag[ki] = a;
        }
        v4f acc[4];
        #pragma unroll
        for (int ct = 0; ct < 4; ++ct) acc[ct] = (v4f){0.f, 0.f, 0.f, 0.f};
        #pragma unroll
        for (int ct = 0; ct < 4; ++ct) {
            #pragma unroll
            for (int ki = 0; ki < 4; ++ki)
                acc[ct] = __builtin_amdgcn_mfma_f32_16x16x32_f16(
                    afrag[ki], sbh[(ct * 4 + ki) * 64 + l], acc[ct], 0, 0, 0);
        }
        _Float16* outh = (_Float16*)xw1h;
        #pragma unroll
        for (int r = 0; r < 4; ++r) {
            int rr = row0 + q * 4 + r;
            if (rr < NN) {
                #pragma unroll
                for (int ct = 0; ct < 4; ++ct)
                    outh[(size_t)rr * HID + ct * 16 + n] = (_Float16)acc[ct][r];
            }
        }
    }
}

// ---------------- per-bucket CSR + dinv + xw1h scaling ----------------
__global__ __launch_bounds__(256) void kB_csr(const int* __restrict__ ebuf,
                                              const int* __restrict__ bucket_fill,
                                              int* __restrict__ pofs,
                                              float* __restrict__ dinv,
                                              int* __restrict__ esrc,
                                              __half* __restrict__ xw1h) {
    __shared__ int lcnt[BN], sA[BN], sB[BN], lcur[BN];
    int t = threadIdx.x;
    int b = blockIdx.x;
    int eb0 = b * SEG;
    int ecnt = bucket_fill[b];
    lcnt[t] = 0; lcnt[t + 256] = 0;
    __syncthreads();
    for (int j = t; j < ecnt; j += 256)
        atomicAdd(&lcnt[ebuf[eb0 + j] & 511], 1);
    __syncthreads();
    sA[t] = lcnt[t]; sA[t + 256] = lcnt[t + 256];
    __syncthreads();
    int* s = sA; int* d = sB;
    for (int off = 1; off < BN; off <<= 1) {
        d[t] = s[t] + ((t >= off) ? s[t - off] : 0);
        int i2 = t + 256;
        d[i2] = s[i2] + ((i2 >= off) ? s[i2 - off] : 0);
        __syncthreads();
        int* tmp = s; s = d; d = tmp;
    }
    int base_node = b * BN;
    #pragma unroll
    for (int k = 0; k < 2; ++k) {
        int i = t + k * 256;
        int excl = s[i] - lcnt[i];
        lcur[i] = excl;
        int node = base_node + i;
        if (node < NN) {
            pofs[node] = ((eb0 + excl) << 10) | lcnt[i];
            dinv[node] = rsqrtf((float)lcnt[i] + 1.0f);   // +1 self-loop
        }
    }
    __syncthreads();
    for (int j = t; j < ecnt; j += 256) {
        int p = ebuf[eb0 + j];
        int r = atomicAdd(&lcur[p & 511], 1);
        esrc[eb0 + r] = p >> 9;
    }
    // scale this bucket's xw1h rows by dinv (k_fat wrote them unscaled)
    float4* xr4 = (float4*)xw1h;
    for (int i = t; i < BN * 8; i += 256) {
        int li = i >> 3;
        int node = base_node + li;
        if (node < NN) {
            float di = rsqrtf((float)lcnt[li] + 1.0f);
            float4 v = xr4[(size_t)node * 8 + (i & 7)];
            __half2* h = (__half2*)&v;
            #pragma unroll
            for (int u = 0; u < 4; ++u) {
                float2 f = __half22float2(h[u]);
                h[u] = __floats2half2_rn(f.x * di, f.y * di);
            }
            xr4[(size_t)node * 8 + (i & 7)] = v;
        }
    }
}

// ---------------- fused: layer-1 aggregation (8-lane groups, b128 gathers) + layer-2 GEMM ----------------
// Phase A: 32 groups x 8 lanes; group handles 2 dsts; lane q loads 16 B
// (channels q*8..q*8+7) -> one wave-instr gathers 8 rows x 128 B.
// Phase B: 4 waves x 16 rows, A-frags from LDS (+bias+relu), 6 MFMAs.
__global__ __launch_bounds__(256) void k_fuse(const __half* __restrict__ xw1h,
                                              const float* __restrict__ dinv,
                                              const int* __restrict__ pofs,
                                              const int* __restrict__ esrc,
                                              const float* __restrict__ b1,
                                              const __half* __restrict__ w2frag,
                                              __half* __restrict__ hw2p) {
    __shared__ float4 sb4[384];          // 6 KB: W2 B-frags
    __shared__ __half sh[64 * 72];       // 9 KB: agg rows, stride 144 B (16B-aligned)
    __shared__ float sb1[64];
    int t = threadIdx.x;
    const float4* wf = (const float4*)w2frag;
    if (t < 192) { sb4[t] = wf[t]; sb4[t + 192] = wf[t + 192]; }
    if (t >= 192) sb1[t - 192] = b1[t - 192];
    int d0 = blockIdx.x * 64;
    int g = t >> 3, q = t & 7;
    const float4* tab4 = (const float4*)xw1h;   // 8 granules (16 B) per row
    #pragma unroll
    for (int sub = 0; sub < 2; ++sub) {
        int d = d0 + g * 2 + sub;
        if (d < NN) {
            float4 lo = make_float4(0.f, 0.f, 0.f, 0.f);
            float4 hi = make_float4(0.f, 0.f, 0.f, 0.f);
            acc8(tab4[(size_t)d * 8 + q], lo, hi);     // self-loop
            int p = pofs[d];
            int j = p >> 10, je = j + (p & 1023);
            for (; j + 7 < je; j += 8) {
                int ss[8];
                #pragma unroll
                for (int u = 0; u < 8; ++u) ss[u] = esrc[j + u];
                float4 vv[8];
                #pragma unroll
                for (int u = 0; u < 8; ++u) vv[u] = tab4[(size_t)ss[u] * 8 + q];
                #pragma unroll
                for (int u = 0; u < 8; ++u) acc8(vv[u], lo, hi);
            }
            for (; j + 3 < je; j += 4) {
                float4 v0 = tab4[(size_t)esrc[j] * 8 + q];
                float4 v1 = tab4[(size_t)esrc[j + 1] * 8 + q];
                float4 v2 = tab4[(size_t)esrc[j + 2] * 8 + q];
                float4 v3 = tab4[(size_t)esrc[j + 3] * 8 + q];
                acc8(v0, lo, hi); acc8(v1, lo, hi);
                acc8(v2, lo, hi); acc8(v3, lo, hi);
            }
            for (; j < je; ++j)
                acc8(tab4[(size_t)esrc[j] * 8 + q], lo, hi);
            float dd = dinv[d];
            float4 st;
            __half2* hp = (__half2*)&st;
            hp[0] = __floats2half2_rn(dd * lo.x, dd * lo.y);
            hp[1] = __floats2half2_rn(dd * lo.z, dd * lo.w);
            hp[2] = __floats2half2_rn(dd * hi.x, dd * hi.y);
            hp[3] = __floats2half2_rn(dd * hi.z, dd * hi.w);
            *(float4*)(sh + (g * 2 + sub) * 72 + q * 8) = st;
        }
    }
    __syncthreads();
    // phase B: 4 waves x 16 rows, A from LDS (+bias+relu), 6 MFMAs
    const v8h* sbh = (const v8h*)sb4;
    int wv = t >> 6, l = t & 63;
    int qq = l >> 4, n = l & 15;
    int srow = wv * 16 + n;
    v8h afrag[2];
    #pragma unroll
    for (int ki = 0; ki < 2; ++ki) {
        v8h a = *(const v8h*)(sh + srow * 72 + ki * 32 + qq * 8);
        #pragma unroll
        for (int j = 0; j < 8; ++j) {
            float av = (float)a[j] + sb1[ki * 32 + qq * 8 + j];
            a[j] = (_Float16)fmaxf(av, 0.f);
        }
        afrag[ki] = a;
    }
    v4f acc[3];
    #pragma unroll
    for (int ct = 0; ct < 3; ++ct) acc[ct] = (v4f){0.f, 0.f, 0.f, 0.f};
    #pragma unroll
    for (int ct = 0; ct < 3; ++ct) {
        #pragma unroll
        for (int ki = 0; ki < 2; ++ki)
            acc[ct] = __builtin_amdgcn_mfma_f32_16x16x32_f16(
                afrag[ki], sbh[(ct * 2 + ki) * 64 + l], acc[ct], 0, 0, 0);
    }
    _Float16* outh = (_Float16*)hw2p;
    #pragma unroll
    for (int r = 0; r < 4; ++r) {
        int rr = d0 + wv * 16 + qq * 4 + r;
        if (rr < NN) {
            float di = dinv[rr];
            #pragma unroll
            for (int ct = 0; ct < 3; ++ct)
                outh[(size_t)rr * 64 + ct * 16 + n] = (_Float16)(acc[ct][r] * di);
        }
    }
}

// ---------------- layer 2 aggregation: 8-lane groups, b128 gathers, 32 dsts/block ----------------
__global__ __launch_bounds__(256) void k_agg2(const __half* __restrict__ hw2p,
                                              const float* __restrict__ dinv,
                                              const int* __restrict__ pofs,
                                              const int* __restrict__ esrc,
                                              const float* __restrict__ b2,
                                              float* __restrict__ out) {
    int t = threadIdx.x;
    int g = t >> 3, q = t & 7;          // lanes q>=5 compute discarded channels
    int d = blockIdx.x * 32 + g;
    if (d >= NN) return;
    const float4* tab4 = (const float4*)hw2p;   // 8 granules per padded row
    float4 lo = make_float4(0.f, 0.f, 0.f, 0.f);
    float4 hi = make_float4(0.f, 0.f, 0.f, 0.f);
    acc8(tab4[(size_t)d * 8 + q], lo, hi);      // self-loop
    int p = pofs[d];
    int j = p >> 10, je = j + (p & 1023);
    for (; j + 7 < je; j += 8) {
        int ss[8];
        #pragma unroll
        for (int u = 0; u < 8; ++u) ss[u] = esrc[j + u];
        float4 vv[8];
        #pragma unroll
        for (int u = 0; u < 8; ++u) vv[u] = tab4[(size_t)ss[u] * 8 + q];
        #pragma unroll
        for (int u = 0; u < 8; ++u) acc8(vv[u], lo, hi);
    }
    for (; j + 3 < je; j += 4) {
        float4 v0 = tab4[(size_t)esrc[j] * 8 + q];
        float4 v1 = tab4[(size_t)esrc[j + 1] * 8 + q];
        float4 v2 = tab4[(size_t)esrc[j + 2] * 8 + q];
        float4 v3 = tab4[(size_t)esrc[j + 3] * 8 + q];
        acc8(v0, lo, hi); acc8(v1, lo, hi);
        acc8(v2, lo, hi); acc8(v3, lo, hi);
    }
    for (; j < je; ++j)
        acc8(tab4[(size_t)esrc[j] * 8 + q], lo, hi);
    if (q < 5) {                         // channels q*8 .. q*8+7 (40 total)
        float dd = dinv[d];
        const float4* b24 = (const float4*)(b2 + q * 8);
        float4 bl = b24[0], bh = b24[1];
        float* op = out + (size_t)d * DOUT + q * 8;
        ((float4*)op)[0] = make_float4(dd * lo.x + bl.x, dd * lo.y + bl.y,
                                       dd * lo.z + bl.z, dd * lo.w + bl.w);
        ((float4*)op)[1] = make_float4(dd * hi.x + bh.x, dd * hi.y + bh.y,
                                       dd * hi.z + bh.z, dd * hi.w + bh.w);
    }
}

extern "C" void kernel_launch(void* const* d_in, const int* in_sizes, int n_in,
                              void* d_out, int out_size, void* d_ws, size_t ws_size,
                              hipStream_t stream) {
    const float* x  = (const float*)d_in[0];
    const float* W1 = (const float*)d_in[1];
    const float* b1 = (const float*)d_in[2];
    const float* W2 = (const float*)d_in[3];
    const float* b2 = (const float*)d_in[4];
    const int*   ei = (const int*)d_in[5];
    const int* src = ei;        // edge_index[0]
    const int* dst = ei + EE;   // edge_index[1]
    float* out = (float*)d_out;

    float* ws = (float*)d_ws;
    int*    bucket_fill = (int*)ws;                     // [0,256)
    int*    pofs        = (int*)ws + 256;               // NN
    float*  dinv        = ws + 100352;                  // NN
    int*    ebuf        = (int*)ws + 200704;            // NB*SEG = 1605632
    int*    esrc        = (int*)ws + 1806336;           // NB*SEG
    __half* xw1h        = (__half*)(ws + 3411968);      // NN*64 halves
    __half* hw2p        = (__half*)(ws + 6611968);      // NN*64 halves (padded rows)
    __half* w1frag      = (__half*)(ws + 9811968);      // 8192 halves
    __half* w2frag      = (__half*)(ws + 9816064);      // 3072 halves
    // total: 9,817,600 floats = 39.3 MB

    k_wprep <<<6, 256, 0, stream>>>(W1, W2, w1frag, w2frag, bucket_fill);
    k_fat   <<<S_BLKS + G_BLKS, 256, 0, stream>>>(src, dst, bucket_fill, ebuf, x, w1frag, xw1h);
    kB_csr  <<<NB, 256, 0, stream>>>(ebuf, bucket_fill, pofs, dinv, esrc, xw1h);
    k_fuse  <<<(NN + 63) / 64, 256, 0, stream>>>(xw1h, dinv, pofs, esrc, b1, w2frag, hw2p);
    k_agg2  <<<(NN + 31) / 32, 256, 0, stream>>>(hw2p, dinv, pofs, esrc, b2, out);
}